// Round 15
// baseline (785.724 us; speedup 1.0000x reference)
//
#include <hip/hip_runtime.h>
#include <math.h>

namespace {

constexpr int Bb = 2, Ss = 1024, Dd = 2048;
constexpr int HQ = 32, HKV = 4, HD = 128;
constexpr int E = 16, I = 768;
constexpr int T = Bb * Ss;                 // 2048 tokens
constexpr int QKVN = HQ * HD + 2 * HKV * HD;  // 5120
constexpr float EPS = 1e-6f;

typedef __attribute__((ext_vector_type(8))) short short8v;
typedef __attribute__((ext_vector_type(4))) float f32x4;

__device__ __forceinline__ unsigned short f2bf(float f) {
  unsigned u = __float_as_uint(f);
  u += 0x7fffu + ((u >> 16) & 1u);   // RNE
  return (unsigned short)(u >> 16);
}
__device__ __forceinline__ float bf2f(unsigned short h) {
  return __uint_as_float((unsigned)h << 16);
}

// global(16B per lane) -> LDS direct; lds_dst must be wave-uniform.
__device__ __forceinline__ void gld_lds16(const void* gsrc, void* lds_dst) {
  __builtin_amdgcn_global_load_lds(
      (const __attribute__((address_space(1))) void*)(unsigned long long)gsrc,
      (__attribute__((address_space(3))) void*)(unsigned)(unsigned long long)lds_dst,
      16, 0, 0);
}

// ---------------- RMS norm over D=2048; fp32 / bf16-hi / bf16-lo outputs ----------------
__global__ __launch_bounds__(256) void rms_kernel(const float* __restrict__ x,
                                                  const float* __restrict__ scale,
                                                  float* __restrict__ outf,
                                                  unsigned short* __restrict__ outh,
                                                  unsigned short* __restrict__ outl) {
  int row = blockIdx.x;
  const float* xr = x + (size_t)row * Dd;
  float ss = 0.f;
  for (int i = threadIdx.x; i < Dd; i += 256) { float v = xr[i]; ss += v * v; }
#pragma unroll
  for (int o = 32; o > 0; o >>= 1) ss += __shfl_xor(ss, o);
  __shared__ float red[4];
  int wave = threadIdx.x >> 6, lane = threadIdx.x & 63;
  if (lane == 0) red[wave] = ss;
  __syncthreads();
  __shared__ float s_r;
  if (threadIdx.x == 0) {
    float tot = red[0] + red[1] + red[2] + red[3];
    s_r = rsqrtf(tot / (float)Dd + EPS);
  }
  __syncthreads();
  float r = s_r;
  for (int i = threadIdx.x; i < Dd; i += 256) {
    float v = xr[i] * r * scale[i];
    if (outf) outf[(size_t)row * Dd + i] = v;
    if (outh) {
      unsigned short hv = f2bf(v);
      outh[(size_t)row * Dd + i] = hv;
      if (outl) outl[(size_t)row * Dd + i] = f2bf(v - bf2f(hv));
    }
  }
}

// ---------------- tiled fp32 -> bf16(hi[,lo]) transpose: out[C][R] = in[R][C] ----------------
__global__ __launch_bounds__(256) void transpose_f32_bf16(
    const float* __restrict__ in, unsigned short* __restrict__ outh,
    unsigned short* __restrict__ outl,
    int R, int C, long in_rs, long out_rs, long in_bs, long out_bs) {
  __shared__ float tile[32][33];
  const float* inb = in + (size_t)blockIdx.z * in_bs;
  int r0 = blockIdx.y * 32, c0 = blockIdx.x * 32;
  int tx = threadIdx.x & 31, ty = threadIdx.x >> 5;  // ty 0..7
#pragma unroll
  for (int i = 0; i < 32; i += 8)
    tile[ty + i][tx] = inb[(size_t)(r0 + ty + i) * in_rs + c0 + tx];
  __syncthreads();
#pragma unroll
  for (int i = 0; i < 32; i += 8) {
    float v = tile[tx][ty + i];
    unsigned short hv = f2bf(v);
    size_t oidx = (size_t)blockIdx.z * out_bs + (size_t)(c0 + ty + i) * out_rs + r0 + tx;
    outh[oidx] = hv;
    if (outl) outl[oidx] = f2bf(v - bf2f(hv));
  }
}

// ---------------- bf16 MFMA GEMM, 64x128 tile ----------------
// C = A(MxK) * BT(NxK)^T (+Cadd). SPLIT: 3-term hi/lo (~fp32 precision).
// NBUF=2: dbuf prefetch (drain). NBUF=3: counted-vmcnt, 2 tiles in flight.
// NBUF=4: counted-vmcnt, 3 tiles in flight.
// 1-D launch, XCD-aware decode:
//   dense (nE==1): 2-D partition — each XCD owns an (M/2 x N/4) rectangle.
//   MoE  (nE>1):  ALL blocks of expert e land on XCD e&7.
// MoE mode via offs/gtok/destb. Cact!=null: paired-silu epilogue.
template <bool SPLIT, int NBUF>
__global__ __launch_bounds__(256) void gemm_bt(
    const unsigned short* __restrict__ Ah, const unsigned short* __restrict__ Al,
    const unsigned short* __restrict__ Bh, const unsigned short* __restrict__ Bl,
    const float* __restrict__ Cadd, float* __restrict__ C,
    int M, int N, int K, int nMb, int nNb, int nE,
    const int* __restrict__ gtok, const int* __restrict__ destb,
    const int* __restrict__ offs, long bt_estride,
    unsigned short* __restrict__ Cact, int ldact) {
  constexpr int NP = SPLIT ? 2 : 1;
  __shared__ alignas(16) unsigned short As[NBUF][NP][64 * 32];
  __shared__ alignas(16) unsigned short Bs[NBUF][NP][128 * 32];
  int bid = blockIdx.x;
  int xcd = bid & 7, rest = bid >> 3;
  int mIdx, nIdx, eIdx;
  if (nE > 1) {
    // expert-major: expert e pinned to XCD e&7 (nE % 8 == 0)
    int gpe = nMb * nNb;                  // blocks per expert
    eIdx = xcd + 8 * (rest / gpe);
    int rem = rest % gpe;
    mIdx = rem % nMb;
    nIdx = rem / nMb;
    if (eIdx >= nE) return;
  } else {
    // dense 2-D: xcd = mh*4 + nq; rest = lm + (nMb/2)*ln  (nMb%2==0, nNb%4==0)
    int nMh = nMb >> 1, nNq = nNb >> 2;
    int mh = xcd >> 2, nq = xcd & 3;
    int lm = rest % nMh, ln = rest / nMh;
    if (ln >= nNq) return;
    mIdx = mh * nMh + lm;
    nIdx = nq * nNq + ln;
    eIdx = 0;
  }

  int base = 0, rows = M;
  const unsigned short* bth = Bh;
  const unsigned short* btl = Bl;
  if (offs) {
    base = offs[eIdx];
    rows = offs[eIdx + 1] - base;
    bth = Bh + (size_t)eIdx * bt_estride;
    if (SPLIT) btl = Bl + (size_t)eIdx * bt_estride;
  }
  int rb = mIdx * 64;
  if (rb >= rows) return;
  int cb = nIdx * 128;
  int tid = threadIdx.x, w = tid >> 6, l = tid & 63;

  // A staging: one row per thread. row = w*16 + (l>>2), k-chunk (l&3)*8.
  size_t ga;
  {
    int ra = rb + w * 16 + (l >> 2);
    if (ra >= rows) ra = rows - 1;
    int gg = offs ? (gtok ? gtok[base + ra] : (base + ra)) : ra;
    ga = (size_t)gg * K + (l & 3) * 8;
  }
  // B staging: two rows per thread: w*32 + j*16 + (l>>2).
  size_t gb0 = (size_t)(cb + w * 32 + (l >> 2)) * K + (l & 3) * 8;
  size_t gb1 = gb0 + (size_t)16 * K;
  unsigned dA = (unsigned)w * 1024;               // LDS byte offsets (wave-uniform)
  unsigned dB0 = (unsigned)w * 2048;
  unsigned dB1 = dB0 + 1024;

  int wr = (w >> 1) * 32, wc = (w & 1) * 64;
  int lrow = l & 15;
  unsigned lk = (unsigned)(l >> 4) * 16;          // byte offset along K
  f32x4 acc[2][4] = {};

  auto STAGE = [&](int buf, int k0) {
    gld_lds16(Ah + ga + k0, (char*)As[buf][0] + dA);
    gld_lds16(bth + gb0 + k0, (char*)Bs[buf][0] + dB0);
    gld_lds16(bth + gb1 + k0, (char*)Bs[buf][0] + dB1);
    if constexpr (SPLIT) {
      gld_lds16(Al + ga + k0, (char*)As[buf][1] + dA);
      gld_lds16(btl + gb0 + k0, (char*)Bs[buf][1] + dB0);
      gld_lds16(btl + gb1 + k0, (char*)Bs[buf][1] + dB1);
    }
  };
  auto COMPUTE = [&](int buf) {
    short8v afh[2], bfh[4];
#pragma unroll
    for (int mi = 0; mi < 2; ++mi)
      afh[mi] = *(const short8v*)((char*)As[buf][0] + (unsigned)(wr + mi * 16 + lrow) * 64 + lk);
#pragma unroll
    for (int ni = 0; ni < 4; ++ni)
      bfh[ni] = *(const short8v*)((char*)Bs[buf][0] + (unsigned)(wc + ni * 16 + lrow) * 64 + lk);
    if constexpr (SPLIT) {
      short8v afl[2], bfl[4];
#pragma unroll
      for (int mi = 0; mi < 2; ++mi)
        afl[mi] = *(const short8v*)((char*)As[buf][1] + (unsigned)(wr + mi * 16 + lrow) * 64 + lk);
#pragma unroll
      for (int ni = 0; ni < 4; ++ni)
        bfl[ni] = *(const short8v*)((char*)Bs[buf][1] + (unsigned)(wc + ni * 16 + lrow) * 64 + lk);
#pragma unroll
      for (int mi = 0; mi < 2; ++mi)
#pragma unroll
        for (int ni = 0; ni < 4; ++ni) {
          acc[mi][ni] = __builtin_amdgcn_mfma_f32_16x16x32_bf16(afh[mi], bfh[ni], acc[mi][ni], 0, 0, 0);
          acc[mi][ni] = __builtin_amdgcn_mfma_f32_16x16x32_bf16(afl[mi], bfh[ni], acc[mi][ni], 0, 0, 0);
          acc[mi][ni] = __builtin_amdgcn_mfma_f32_16x16x32_bf16(afh[mi], bfl[ni], acc[mi][ni], 0, 0, 0);
        }
    } else {
#pragma unroll
      for (int mi = 0; mi < 2; ++mi)
#pragma unroll
        for (int ni = 0; ni < 4; ++ni)
          acc[mi][ni] = __builtin_amdgcn_mfma_f32_16x16x32_bf16(afh[mi], bfh[ni], acc[mi][ni], 0, 0, 0);
    }
  };

  int NT = K / 32;
  if constexpr (NBUF == 2) {
    STAGE(0, 0);
    asm volatile("s_waitcnt vmcnt(0)" ::: "memory");
    __syncthreads();
    int cur = 0;
    for (int t = 0; t < NT; ++t) {
      if (t + 1 < NT) STAGE(cur ^ 1, (t + 1) * 32);
      COMPUTE(cur);
      asm volatile("s_waitcnt vmcnt(0)" ::: "memory");
      __syncthreads();
      cur ^= 1;
    }
  } else if constexpr (NBUF == 3) {
    // 3-buf: 2 tiles in flight, counted vmcnt (L=3 or 6 loads/STAGE), raw barrier.
    STAGE(0, 0);
    if (NT > 1) STAGE(1, 32);
    for (int t = 0; t < NT; ++t) {
      if (t + 1 < NT) {
        if constexpr (SPLIT) asm volatile("s_waitcnt vmcnt(6)" ::: "memory");
        else                 asm volatile("s_waitcnt vmcnt(3)" ::: "memory");
      } else {
        asm volatile("s_waitcnt vmcnt(0)" ::: "memory");
      }
      __builtin_amdgcn_s_barrier();   // all waves done reading buf (t-1)%3
      if (t + 2 < NT) STAGE((t + 2) % 3, (t + 2) * 32);
      COMPUTE(t % 3);
    }
  } else {
    // 4-buf: 3 tiles in flight, counted vmcnt (L=3 or 6 loads/STAGE), raw barrier.
    STAGE(0, 0);
    if (NT > 1) STAGE(1, 32);
    if (NT > 2) STAGE(2, 64);
    for (int t = 0; t < NT; ++t) {
      if (t + 2 < NT) {
        if constexpr (SPLIT) asm volatile("s_waitcnt vmcnt(12)" ::: "memory");
        else                 asm volatile("s_waitcnt vmcnt(6)" ::: "memory");
      } else if (t + 1 < NT) {
        if constexpr (SPLIT) asm volatile("s_waitcnt vmcnt(6)" ::: "memory");
        else                 asm volatile("s_waitcnt vmcnt(3)" ::: "memory");
      } else {
        asm volatile("s_waitcnt vmcnt(0)" ::: "memory");
      }
      __builtin_amdgcn_s_barrier();   // all waves' tile-t stages visible; bounds skew
      if (t + 3 < NT) STAGE((t + 3) & 3, (t + 3) * 32);
      COMPUTE(t & 3);
    }
  }

  int lr4 = (l >> 4) << 2;
  if (Cact) {
    // paired-silu epilogue: n even = gate, n odd = up (same logical col n>>1)
#pragma unroll
    for (int mi = 0; mi < 2; ++mi) {
#pragma unroll
      for (int reg = 0; reg < 4; ++reg) {
        int rl = wr + mi * 16 + lr4 + reg;
        int rr = rb + rl;
        bool valid = !(offs && rr >= rows);
        size_t orow = 0;
        if (valid) orow = (size_t)(destb ? destb[base + rr] : (base + rr));
#pragma unroll
        for (int ni = 0; ni < 4; ++ni) {
          float v = acc[mi][ni][reg];
          float other = __shfl_xor(v, 1);
          if (valid && !(l & 1)) {
            float s = 1.f / (1.f + __expf(-v));
            int n = cb + wc + ni * 16 + (l & 15);
            Cact[orow * (size_t)ldact + (n >> 1)] = f2bf(v * s * other);
          }
        }
      }
    }
  } else {
#pragma unroll
    for (int mi = 0; mi < 2; ++mi) {
#pragma unroll
      for (int reg = 0; reg < 4; ++reg) {
        int rl = wr + mi * 16 + lr4 + reg;
        int rr = rb + rl;
        if (offs && rr >= rows) continue;
        size_t orow;
        if (!offs) orow = (size_t)rr;
        else orow = (size_t)(destb ? destb[base + rr] : (base + rr));
        float* crow = C + orow * N + cb + wc + (l & 15);
        const float* arow = Cadd ? (Cadd + orow * N + cb + wc + (l & 15)) : nullptr;
#pragma unroll
        for (int ni = 0; ni < 4; ++ni) {
          float v = acc[mi][ni][reg];
          if (Cadd) v += arow[ni * 16];
          crow[ni * 16] = v;
        }
      }
    }
  }
}

// ---------------- per-head RMS + mROPE, IN-PLACE split-bf16 conversion ----------------
__global__ __launch_bounds__(256) void qknorm_rope(
    float* __restrict__ qkv, const float* __restrict__ scale,
    const int* __restrict__ pos, int H, int coff) {
  int wid = (blockIdx.x * 256 + threadIdx.x) >> 6;
  int lane = threadIdx.x & 63;
  int t = wid / H, hh = wid % H;
  float* row = qkv + (size_t)t * QKVN + coff + hh * 128;
  float v0 = row[lane], v1 = row[lane + 64];
  float ss = v0 * v0 + v1 * v1;
#pragma unroll
  for (int o = 32; o > 0; o >>= 1) ss += __shfl_xor(ss, o);
  float r = rsqrtf(ss / 128.f + EPS);
  float n0 = v0 * r * scale[lane];
  float n1 = v1 * r * scale[lane + 64];
  int axis = lane < 24 ? 0 : (lane < 44 ? 1 : 2);
  float p = (float)pos[axis * T + t];
  float inv = exp2f(-19.931568569324174f * ((float)lane * (1.0f / 64.0f)));
  float f = p * inv;
  float sn, cs;
  sincosf(f, &sn, &cs);
  float o0 = n0 * cs - n1 * sn;
  float o1 = n1 * cs + n0 * sn;
  unsigned short h0 = f2bf(o0), h1 = f2bf(o1);
  unsigned short* o = (unsigned short*)row;
  o[lane] = h0;
  o[lane + 64] = h1;
  o[128 + lane] = f2bf(o0 - bf2f(h0));
  o[192 + lane] = f2bf(o1 - bf2f(h1));
}

// ---------------- MFMA causal GQA flash attention, split-bf16 (3-term) ----------------
// LDS-staged K/V, double-buffered with async prefetch (one barrier per KV tile).
// Lazy defer-max (shuffle tree only when max grows >8), lsum via MFMA-ones,
// fully-masked-tile compute skip, LPT launch order (heavy q-tiles first).
__global__ __launch_bounds__(256) void flash_mfma(
    const char* __restrict__ qkvb, const unsigned short* __restrict__ Vth,
    const unsigned short* __restrict__ Vtl,
    unsigned short* __restrict__ Aoh, unsigned short* __restrict__ Aol) {
  __shared__ alignas(16) unsigned short Ks[2][2][32 * 128];   // [buf][hi/lo][key][d], swizzled
  __shared__ alignas(16) unsigned short Vs[2][2][128 * 32];   // [buf][hi/lo][d][key], swizzled
  __shared__ alignas(16) unsigned short Ps[2][4 * 16 * 32];   // [hi/lo] per-wave [q][key]
  int by = blockIdx.y;
  int b = by >> 5, h = by & 31, kvh = h >> 3;
  int qb0 = (int)(gridDim.x - 1 - blockIdx.x) * 64;   // LPT: heavy blocks first
  int tid = threadIdx.x, w = tid >> 6, l = tid & 63;

  short8v aqh[4], aql[4];
  {
    const char* qrow = qkvb + (size_t)(b * Ss + qb0 + w * 16 + (l & 15)) * 20480
                       + h * 512 + (l >> 4) * 16;
#pragma unroll
    for (int kc = 0; kc < 4; ++kc) {
      aqh[kc] = *(const short8v*)(qrow + kc * 64);
      aql[kc] = *(const short8v*)(qrow + 256 + kc * 64);
    }
  }
  short8v vone;
#pragma unroll
  for (int j = 0; j < 8; ++j) vone[j] = (short)0x3F80;   // bf16 1.0
  f32x4 oacc[8] = {};
  float mrow[4], lsum[4];
#pragma unroll
  for (int r = 0; r < 4; ++r) { mrow[r] = -1e30f; lsum[r] = 0.f; }
  const float sc = 0.08838834764831845f;  // 1/sqrt(128)
  int qgbase = qb0 + w * 16 + ((l >> 4) << 2);
  int ntiles = qb0 / 32 + 2;              // block-uniform (barrier-synced loop)
  int wmaxrow = qb0 + w * 16 + 15;        // this wave's last q row

  auto STAGE = [&](int buf, int kt) {
#pragma unroll
    for (int j = 0; j < 2; ++j) {
      int row = w * 8 + j * 4 + (l >> 4);
      unsigned scol = (unsigned)((l & 15) * 16) ^ ((unsigned)(row & 7) << 4);
      const char* src = qkvb + (size_t)(b * Ss + kt * 32 + row) * 20480
                        + 16384 + kvh * 512 + scol;
      gld_lds16(src, (char*)Ks[buf][0] + (w * 8 + j * 4) * 256);
      gld_lds16(src + 256, (char*)Ks[buf][1] + (w * 8 + j * 4) * 256);
    }
#pragma unroll
    for (int j = 0; j < 2; ++j) {
      int d = w * 32 + j * 16 + (l >> 2);
      unsigned scol = (unsigned)((l & 3) * 16) ^ ((unsigned)(d & 3) << 4);
      size_t vo = (((size_t)(b * HKV + kvh) * 128 + d) * 1024 + kt * 32) * 2 + scol;
      gld_lds16((const char*)Vth + vo, (char*)Vs[buf][0] + (w * 32 + j * 16) * 64);
      gld_lds16((const char*)Vtl + vo, (char*)Vs[buf][1] + (w * 32 + j * 16) * 64);
    }
  };

  STAGE(0, 0);
  asm volatile("s_waitcnt vmcnt(0)" ::: "memory");
  __syncthreads();

  int cur = 0;
  for (int kt = 0; kt < ntiles; ++kt) {
    if (kt + 1 < ntiles) STAGE(cur ^ 1, kt + 1);

    if (kt * 32 <= wmaxrow) {   // wave has at least one unmasked key this tile
      f32x4 s[2] = {};
#pragma unroll
      for (int nt = 0; nt < 2; ++nt) {
        int krow = nt * 16 + (l & 15);
#pragma unroll
        for (int kc = 0; kc < 4; ++kc) {
          unsigned colb = ((unsigned)(kc * 64 + (l >> 4) * 16)) ^ ((unsigned)(krow & 7) << 4);
          short8v bkh = *(const short8v*)((char*)Ks[cur][0] + (unsigned)krow * 256 + colb);
          short8v bkl = *(const short8v*)((char*)Ks[cur][1] + (unsigned)krow * 256 + colb);
          s[nt] = __builtin_amdgcn_mfma_f32_16x16x32_bf16(aqh[kc], bkh, s[nt], 0, 0, 0);
          s[nt] = __builtin_amdgcn_mfma_f32_16x16x32_bf16(aql[kc], bkh, s[nt], 0, 0, 0);
          s[nt] = __builtin_amdgcn_mfma_f32_16x16x32_bf16(aqh[kc], bkl, s[nt], 0, 0, 0);
        }
      }
      // mask + per-lane tile max (no reduction in common path)
      float pv[2][4], tmax[4];
#pragma unroll
      for (int r = 0; r < 4; ++r) tmax[r] = -1e30f;
#pragma unroll
      for (int nt = 0; nt < 2; ++nt) {
        int key = kt * 32 + nt * 16 + (l & 15);
#pragma unroll
        for (int r = 0; r < 4; ++r) {
          float v = s[nt][r] * sc;
          if (key > qgbase + r) v = -1e30f;
          pv[nt][r] = v;
          tmax[r] = fmaxf(tmax[r], v);
        }
      }
      // lazy defer-max: tree + rescale only when some lane's max grew > 8
      bool need = false;
#pragma unroll
      for (int r = 0; r < 4; ++r) need = need || (tmax[r] > mrow[r] + 8.f);
      if (__any(need)) {
#pragma unroll
        for (int o = 1; o < 16; o <<= 1)
#pragma unroll
          for (int r = 0; r < 4; ++r) tmax[r] = fmaxf(tmax[r], __shfl_xor(tmax[r], o));
#pragma unroll
        for (int r = 0; r < 4; ++r) {
          float mn = fmaxf(mrow[r], tmax[r]);
          float corr = __expf(mrow[r] - mn);
          mrow[r] = mn;
          lsum[r] *= corr;
#pragma unroll
          for (int n2 = 0; n2 < 8; ++n2) oacc[n2][r] *= corr;
        }
      }
      // P = exp(S - mrow) (bounded by e^8), split to bf16 hi/lo in LDS
#pragma unroll
      for (int nt = 0; nt < 2; ++nt)
#pragma unroll
        for (int r = 0; r < 4; ++r) {
          float p = __expf(pv[nt][r] - mrow[r]);
          unsigned short ph = f2bf(p);
          unsigned short pl = f2bf(p - bf2f(ph));
          int q = ((l >> 4) << 2) + r;
          int key = nt * 16 + (l & 15);
          unsigned pb = w * 1024 + q * 64 + (((unsigned)key * 2) ^ ((unsigned)(q & 3) << 4));
          *(unsigned short*)((char*)Ps[0] + pb) = ph;
          *(unsigned short*)((char*)Ps[1] + pb) = pl;
        }
      unsigned pr = w * 1024 + (l & 15) * 64 +
                    (((unsigned)(l >> 4) * 16) ^ ((unsigned)(l & 3) << 4));
      short8v pah = *(const short8v*)((char*)Ps[0] + pr);
      short8v pal = *(const short8v*)((char*)Ps[1] + pr);
      // row-sum via MFMA with ones-B: out[q][*] = sum_k P[q][k], layout matches lsum[r]
      {
        f32x4 rs = {};
        rs = __builtin_amdgcn_mfma_f32_16x16x32_bf16(pah, vone, rs, 0, 0, 0);
        rs = __builtin_amdgcn_mfma_f32_16x16x32_bf16(pal, vone, rs, 0, 0, 0);
#pragma unroll
        for (int r = 0; r < 4; ++r) lsum[r] += rs[r];
      }
#pragma unroll
      for (int n2 = 0; n2 < 8; ++n2) {
        int d = n2 * 16 + (l & 15);
        unsigned vb = (unsigned)d * 64 +
                      (((unsigned)(l >> 4) * 16) ^ ((unsigned)(d & 3) << 4));
        short8v bvh = *(const short8v*)((char*)Vs[cur][0] + vb);
        short8v bvl = *(const short8v*)((char*)Vs[cur][1] + vb);
        oacc[n2] = __builtin_amdgcn_mfma_f32_16x16x32_bf16(pah, bvh, oacc[n2], 0, 0, 0);
        oacc[n2] = __builtin_amdgcn_mfma_f32_16x16x32_bf16(pal, bvh, oacc[n2], 0, 0, 0);
        oacc[n2] = __builtin_amdgcn_mfma_f32_16x16x32_bf16(pah, bvl, oacc[n2], 0, 0, 0);
      }
    }
    asm volatile("s_waitcnt vmcnt(0)" ::: "memory");
    __syncthreads();
    cur ^= 1;
  }
#pragma unroll
  for (int r = 0; r < 4; ++r) {
    float inv = 1.f / lsum[r];
    size_t obase = (size_t)(b * Ss + qgbase + r) * 4096 + h * 128 + (l & 15);
#pragma unroll
    for (int n2 = 0; n2 < 8; ++n2) {
      float v = oacc[n2][r] * inv;
      unsigned short hv = f2bf(v);
      Aoh[obase + n2 * 16] = hv;
      Aol[obase + n2 * 16] = f2bf(v - bf2f(hv));
    }
  }
}

// ---------------- router (fp32 h), top-2, counts ----------------
__global__ __launch_bounds__(64) void router_kernel(const float* __restrict__ H,
                                                    const float* __restrict__ RW,
                                                    float* __restrict__ pslot,
                                                    int* __restrict__ topi,
                                                    int* __restrict__ counts) {
  int t = blockIdx.x;
  int lane = threadIdx.x;
  float part[E] = {};
  const float* hrow = H + (size_t)t * Dd;
  for (int d = lane; d < Dd; d += 64) {
    float hv = hrow[d];
    const float* rw = RW + (size_t)d * E;
#pragma unroll
    for (int e = 0; e < E; ++e) part[e] = fmaf(hv, rw[e], part[e]);
  }
#pragma unroll
  for (int e = 0; e < E; ++e)
#pragma unroll
    for (int o = 32; o > 0; o >>= 1) part[e] += __shfl_xor(part[e], o);
  if (lane == 0) {
    float mx = part[0];
#pragma unroll
    for (int e = 1; e < E; ++e) mx = fmaxf(mx, part[e]);
    float p[E];
#pragma unroll
    for (int e = 0; e < E; ++e) p[e] = __expf(part[e] - mx);
    int i0 = 0;
#pragma unroll
    for (int e = 1; e < E; ++e) if (p[e] > p[i0]) i0 = e;
    int i1 = (i0 == 0) ? 1 : 0;
#pragma unroll
    for (int e = 0; e < E; ++e) if (e != i0 && p[e] > p[i1]) i1 = e;
    float p0 = p[i0], p1 = p[i1];
    float denom = p0 + p1;
    pslot[2 * t] = p0 / denom;
    pslot[2 * t + 1] = p1 / denom;
    topi[2 * t] = i0;
    topi[2 * t + 1] = i1;
    atomicAdd(&counts[i0], 1);
    atomicAdd(&counts[i1], 1);
  }
}

__global__ void offsets_kernel(const int* __restrict__ counts, int* __restrict__ offs) {
  if (threadIdx.x == 0) {
    int s = 0;
    for (int e = 0; e < E; ++e) { offs[e] = s; s += counts[e]; }
    offs[E] = s;
  }
}

__global__ __launch_bounds__(256) void scatter_kernel(const int* __restrict__ topi,
                                                      const int* __restrict__ offs,
                                                      int* __restrict__ fill,
                                                      int* __restrict__ gtok,
                                                      int* __restrict__ destb) {
  int t = blockIdx.x * 256 + threadIdx.x;
  if (t >= T) return;
#pragma unroll
  for (int slot = 0; slot < 2; ++slot) {
    int e = topi[2 * t + slot];
    int pos = offs[e] + atomicAdd(&fill[e], 1);
    gtok[pos] = t;
    destb[pos] = 2 * t + slot;
  }
}

__global__ __launch_bounds__(256) void combine_kernel(float* __restrict__ out,
                                                      const float* __restrict__ eo,
                                                      const float* __restrict__ pslot) {
  int i = blockIdx.x * 256 + threadIdx.x;  // < T*D
  int t = i >> 11;
  int d = i & 2047;
  out[i] += pslot[2 * t] * eo[((size_t)(2 * t) << 11) + d] +
            pslot[2 * t + 1] * eo[((size_t)(2 * t + 1) << 11) + d];
}

}  // namespace

extern "C" void kernel_launch(void* const* d_in, const int* in_sizes, int n_in,
                              void* d_out, int out_size, void* d_ws, size_t ws_size,
                              hipStream_t stream) {
  (void)in_sizes; (void)n_in; (void)out_size; (void)ws_size;
  const float* x = (const float*)d_in[0];
  const int* pos = (const int*)d_in[1];
  const float* pre_s = (const float*)d_in[2];
  const float* wq = (const float*)d_in[3];
  const float* wk = (const float*)d_in[4];
  const float* wv = (const float*)d_in[5];
  const float* wo = (const float*)d_in[6];
  const float* qns = (const float*)d_in[7];
  const float* kns = (const float*)d_in[8];
  const float* post_s = (const float*)d_in[9];
  const float* rw = (const float*)d_in[10];
  const float* gw = (const float*)d_in[11];
  const float* uw = (const float*)d_in[12];
  const float* dw = (const float*)d_in[13];
  float* out = (float*)d_out;
  char* ws = (char*)d_ws;

  // ---- workspace (phase-aliased; MiB offsets; peak ~140 MiB) ----
  unsigned short* hbh = (unsigned short*)(ws + 0);            // [0,8)
  unsigned short* hbl = (unsigned short*)(ws + 8388608);      // [8,16)
  const size_t W0 = 16777216;                                 // [16,64) attn weights
  unsigned short* wqkvTh = (unsigned short*)(ws + W0);
  unsigned short* wqkvTl = (unsigned short*)(ws + W0 + 20971520);
  unsigned short* woTh = (unsigned short*)(ws + W0);          // after QKV gemm
  unsigned short* woTl = (unsigned short*)(ws + W0 + 16777216);
  const size_t X0 = 67108864;                                 // [64,104) qkv / h
  float* qkv = (float*)(ws + X0);
  float* h = (float*)(ws + X0);                               // router input
  const size_t A0 = 109051904;                                // [104,136) attn out
  unsigned short* aoh = (unsigned short*)(ws + A0);
  unsigned short* aol = (unsigned short*)(ws + A0 + 16777216);
  unsigned short* vth = (unsigned short*)(ws + 142606336);    // [136,138)
  unsigned short* vtl = (unsigned short*)(ws + 144703488);    // [138,140)
  // MoE phase (all pre-MoE data dead when each region is written):
  unsigned short* moeGU = (unsigned short*)(ws + 16777216);   // [16,112)  E x 1536 x 2048 bf16 (interleaved gate/up rows)
  unsigned short* actb = (unsigned short*)(ws + 117440512);   // [112,118.3) 4096 x 768 bf16 (GU GEMM epilogue)
  unsigned short* moeD = (unsigned short*)(ws + 16777216);    // [16,64)   E x 2048 x 768 bf16 (after GU GEMM)
  float* eo = (float*)(ws + 67108864);                        // [64,96)   4096 x 2048 fp32 (h dead by then)
  const size_t RT = 146800640;                                // [140,...) router scratch
  float* pslot = (float*)(ws + RT);
  int* topi = (int*)(ws + RT + 16384);
  int* counts = (int*)(ws + RT + 32768);
  int* fill = counts + 16;
  int* offs = fill + 16;
  int* gtok = (int*)(ws + RT + 33280);
  int* destb = gtok + 2 * T;

  // 1. QKV weight transposes (split hi/lo, B^T layout)
  transpose_f32_bf16<<<dim3(128, 64, 1), 256, 0, stream>>>(wq, wqkvTh, wqkvTl, Dd, 4096, 4096, 2048, 0, 0);
  transpose_f32_bf16<<<dim3(16, 64, 1), 256, 0, stream>>>(wk, wqkvTh + (size_t)4096 * 2048, wqkvTl + (size_t)4096 * 2048, Dd, 512, 512, 2048, 0, 0);
  transpose_f32_bf16<<<dim3(16, 64, 1), 256, 0, stream>>>(wv, wqkvTh + (size_t)4608 * 2048, wqkvTl + (size_t)4608 * 2048, Dd, 512, 512, 2048, 0, 0);
  // 2. pre-RMS (split bf16)
  rms_kernel<<<T, 256, 0, stream>>>(x, pre_s, nullptr, hbh, hbl);
  // 3. fused QKV split GEMM -> qkv fp32 (T x 5120); 2-D XCD partition, 3-buf pipeline
  gemm_bt<true, 3><<<32 * 40, 256, 0, stream>>>(hbh, hbl, wqkvTh, wqkvTl, nullptr, qkv,
                                                T, QKVN, Dd, 32, 40, 1,
                                                nullptr, nullptr, nullptr, 0, nullptr, 0);
  // 4. qk norm + rope, in-place split-bf16
  qknorm_rope<<<T * HQ / 4, 256, 0, stream>>>(qkv, qns, pos, HQ, 0);
  qknorm_rope<<<T * HKV / 4, 256, 0, stream>>>(qkv, kns, pos, HKV, 4096);
  // 5. V transpose -> vt[b][kvh][d][s] split bf16
  for (int b = 0; b < Bb; ++b)
    transpose_f32_bf16<<<dim3(4, 32, HKV), 256, 0, stream>>>(
        qkv + (size_t)b * Ss * QKVN + 4608, vth + (size_t)b * HKV * 131072,
        vtl + (size_t)b * HKV * 131072, Ss, HD, QKVN, Ss, 128, 131072);
  // 6. wo transpose (split) into W region (wqkvT dead)
  transpose_f32_bf16<<<dim3(64, 128, 1), 256, 0, stream>>>(wo, woTh, woTl, 4096, Dd, 2048, 4096, 0, 0);
  // 7. split MFMA flash attention (LDS dbuf prefetch) -> ao hi/lo
  flash_mfma<<<dim3(Ss / 64, Bb * HQ), 256, 0, stream>>>((const char*)(ws + X0), vth, vtl, aoh, aol);
  // 8. O-proj split GEMM + residual -> out fp32; 2-D XCD partition, 3-buf pipeline
  gemm_bt<true, 3><<<32 * 16, 256, 0, stream>>>(aoh, aol, woTh, woTl, x, out,
                                                T, Dd, HQ * HD, 32, 16, 1,
                                                nullptr, nullptr, nullptr, 0, nullptr, 0);
  // 9. post-RMS (fp32 h for router + plain bf16 for experts)
  rms_kernel<<<T, 256, 0, stream>>>(out, post_s, h, hbh, nullptr);
  // 10. router + expert grouping
  hipMemsetAsync(counts, 0, 2 * E * sizeof(int), stream);
  router_kernel<<<T, 64, 0, stream>>>(h, rw, pslot, topi, counts);
  offsets_kernel<<<1, 64, 0, stream>>>(counts, offs);
  scatter_kernel<<<T / 256, 256, 0, stream>>>(topi, offs, fill, gtok, destb);
  // 11. MoE: gate/up transposed INTERLEAVED (gate col j -> row 2j, up -> 2j+1)
  transpose_f32_bf16<<<dim3(24, 64, E), 256, 0, stream>>>(gw, moeGU, nullptr, Dd, I, I, 4096,
                                                          (long)Dd * I, (long)1536 * 2048);
  transpose_f32_bf16<<<dim3(24, 64, E), 256, 0, stream>>>(uw, moeGU + 2048, nullptr, Dd, I, I, 4096,
                                                          (long)Dd * I, (long)1536 * 2048);
  // 12. ONE grouped GEMM with fused silu epilogue -> actb bf16 (4-buf, expert-pinned XCDs)
  gemm_bt<false, 4><<<32 * 12 * E, 256, 0, stream>>>(hbh, nullptr, moeGU, nullptr, nullptr, nullptr,
                                                     0, 1536, Dd, 32, 12, E,
                                                     gtok, nullptr, offs, (long)1536 * 2048,
                                                     actb, I);
  // 13. down: transpose then grouped GEMM (4-buf, expert-pinned XCDs), scatter rows
  transpose_f32_bf16<<<dim3(64, 24, E), 256, 0, stream>>>(dw, moeD, nullptr, I, Dd, Dd, I,
                                                          (long)I * Dd, (long)Dd * I);
  gemm_bt<false, 4><<<32 * 16 * E, 256, 0, stream>>>(actb, nullptr, moeD, nullptr, nullptr, eo,
                                                     0, Dd, I, 32, 16, E,
                                                     nullptr, destb, offs, (long)Dd * I,
                                                     nullptr, 0);
  // 14. weighted combine into residual
  combine_kernel<<<(T * Dd) / 256, 256, 0, stream>>>(out, eo, pslot);
}

// Round 16
// 776.795 us; speedup vs baseline: 1.0115x; 1.0115x over previous
//
#include <hip/hip_runtime.h>
#include <math.h>

namespace {

constexpr int Bb = 2, Ss = 1024, Dd = 2048;
constexpr int HQ = 32, HKV = 4, HD = 128;
constexpr int E = 16, I = 768;
constexpr int T = Bb * Ss;                 // 2048 tokens
constexpr int QKVN = HQ * HD + 2 * HKV * HD;  // 5120
constexpr float EPS = 1e-6f;

typedef __attribute__((ext_vector_type(8))) short short8v;
typedef __attribute__((ext_vector_type(4))) float f32x4;

__device__ __forceinline__ unsigned short f2bf(float f) {
  unsigned u = __float_as_uint(f);
  u += 0x7fffu + ((u >> 16) & 1u);   // RNE
  return (unsigned short)(u >> 16);
}
__device__ __forceinline__ float bf2f(unsigned short h) {
  return __uint_as_float((unsigned)h << 16);
}

// global(16B per lane) -> LDS direct; lds_dst must be wave-uniform.
__device__ __forceinline__ void gld_lds16(const void* gsrc, void* lds_dst) {
  __builtin_amdgcn_global_load_lds(
      (const __attribute__((address_space(1))) void*)(unsigned long long)gsrc,
      (__attribute__((address_space(3))) void*)(unsigned)(unsigned long long)lds_dst,
      16, 0, 0);
}

// ---------------- RMS norm over D=2048; fp32 / bf16-hi / bf16-lo outputs ----------------
__global__ __launch_bounds__(256) void rms_kernel(const float* __restrict__ x,
                                                  const float* __restrict__ scale,
                                                  float* __restrict__ outf,
                                                  unsigned short* __restrict__ outh,
                                                  unsigned short* __restrict__ outl) {
  int row = blockIdx.x;
  const float* xr = x + (size_t)row * Dd;
  float ss = 0.f;
  for (int i = threadIdx.x; i < Dd; i += 256) { float v = xr[i]; ss += v * v; }
#pragma unroll
  for (int o = 32; o > 0; o >>= 1) ss += __shfl_xor(ss, o);
  __shared__ float red[4];
  int wave = threadIdx.x >> 6, lane = threadIdx.x & 63;
  if (lane == 0) red[wave] = ss;
  __syncthreads();
  __shared__ float s_r;
  if (threadIdx.x == 0) {
    float tot = red[0] + red[1] + red[2] + red[3];
    s_r = rsqrtf(tot / (float)Dd + EPS);
  }
  __syncthreads();
  float r = s_r;
  for (int i = threadIdx.x; i < Dd; i += 256) {
    float v = xr[i] * r * scale[i];
    if (outf) outf[(size_t)row * Dd + i] = v;
    if (outh) {
      unsigned short hv = f2bf(v);
      outh[(size_t)row * Dd + i] = hv;
      if (outl) outl[(size_t)row * Dd + i] = f2bf(v - bf2f(hv));
    }
  }
}

// ---------------- tiled fp32 -> bf16(hi[,lo]) transpose: out[C][R] = in[R][C] ----------------
__global__ __launch_bounds__(256) void transpose_f32_bf16(
    const float* __restrict__ in, unsigned short* __restrict__ outh,
    unsigned short* __restrict__ outl,
    int R, int C, long in_rs, long out_rs, long in_bs, long out_bs) {
  __shared__ float tile[32][33];
  const float* inb = in + (size_t)blockIdx.z * in_bs;
  int r0 = blockIdx.y * 32, c0 = blockIdx.x * 32;
  int tx = threadIdx.x & 31, ty = threadIdx.x >> 5;  // ty 0..7
#pragma unroll
  for (int i = 0; i < 32; i += 8)
    tile[ty + i][tx] = inb[(size_t)(r0 + ty + i) * in_rs + c0 + tx];
  __syncthreads();
#pragma unroll
  for (int i = 0; i < 32; i += 8) {
    float v = tile[tx][ty + i];
    unsigned short hv = f2bf(v);
    size_t oidx = (size_t)blockIdx.z * out_bs + (size_t)(c0 + ty + i) * out_rs + r0 + tx;
    outh[oidx] = hv;
    if (outl) outl[oidx] = f2bf(v - bf2f(hv));
  }
}

// ---------------- bf16 MFMA GEMM, 64x128 tile ----------------
// C = A(MxK) * BT(NxK)^T (+Cadd). SPLIT: 3-term hi/lo (~fp32 precision).
// NBUF=2: dbuf prefetch (drain) — best for split (48 KB LDS, 2+ blocks/CU).
// NBUF=4: counted-vmcnt pipeline (3 tiles in flight) — best for non-split MoE.
// 1-D launch, XCD-aware decode:
//   dense (nE==1): 2-D partition — each XCD owns an (M/2 x N/4) rectangle.
//   MoE  (nE>1):  ALL blocks of expert e land on XCD e&7.
// MoE mode via offs/gtok/destb. Cact!=null: paired-silu epilogue.
template <bool SPLIT, int NBUF>
__global__ __launch_bounds__(256) void gemm_bt(
    const unsigned short* __restrict__ Ah, const unsigned short* __restrict__ Al,
    const unsigned short* __restrict__ Bh, const unsigned short* __restrict__ Bl,
    const float* __restrict__ Cadd, float* __restrict__ C,
    int M, int N, int K, int nMb, int nNb, int nE,
    const int* __restrict__ gtok, const int* __restrict__ destb,
    const int* __restrict__ offs, long bt_estride,
    unsigned short* __restrict__ Cact, int ldact) {
  constexpr int NP = SPLIT ? 2 : 1;
  __shared__ alignas(16) unsigned short As[NBUF][NP][64 * 32];
  __shared__ alignas(16) unsigned short Bs[NBUF][NP][128 * 32];
  int bid = blockIdx.x;
  int xcd = bid & 7, rest = bid >> 3;
  int mIdx, nIdx, eIdx;
  if (nE > 1) {
    // expert-major: expert e pinned to XCD e&7 (nE % 8 == 0)
    int gpe = nMb * nNb;                  // blocks per expert
    eIdx = xcd + 8 * (rest / gpe);
    int rem = rest % gpe;
    mIdx = rem % nMb;
    nIdx = rem / nMb;
    if (eIdx >= nE) return;
  } else {
    // dense 2-D: xcd = mh*4 + nq; rest = lm + (nMb/2)*ln  (nMb%2==0, nNb%4==0)
    int nMh = nMb >> 1, nNq = nNb >> 2;
    int mh = xcd >> 2, nq = xcd & 3;
    int lm = rest % nMh, ln = rest / nMh;
    if (ln >= nNq) return;
    mIdx = mh * nMh + lm;
    nIdx = nq * nNq + ln;
    eIdx = 0;
  }

  int base = 0, rows = M;
  const unsigned short* bth = Bh;
  const unsigned short* btl = Bl;
  if (offs) {
    base = offs[eIdx];
    rows = offs[eIdx + 1] - base;
    bth = Bh + (size_t)eIdx * bt_estride;
    if (SPLIT) btl = Bl + (size_t)eIdx * bt_estride;
  }
  int rb = mIdx * 64;
  if (rb >= rows) return;
  int cb = nIdx * 128;
  int tid = threadIdx.x, w = tid >> 6, l = tid & 63;

  // A staging: one row per thread. row = w*16 + (l>>2), k-chunk (l&3)*8.
  size_t ga;
  {
    int ra = rb + w * 16 + (l >> 2);
    if (ra >= rows) ra = rows - 1;
    int gg = offs ? (gtok ? gtok[base + ra] : (base + ra)) : ra;
    ga = (size_t)gg * K + (l & 3) * 8;
  }
  // B staging: two rows per thread: w*32 + j*16 + (l>>2).
  size_t gb0 = (size_t)(cb + w * 32 + (l >> 2)) * K + (l & 3) * 8;
  size_t gb1 = gb0 + (size_t)16 * K;
  unsigned dA = (unsigned)w * 1024;               // LDS byte offsets (wave-uniform)
  unsigned dB0 = (unsigned)w * 2048;
  unsigned dB1 = dB0 + 1024;

  int wr = (w >> 1) * 32, wc = (w & 1) * 64;
  int lrow = l & 15;
  unsigned lk = (unsigned)(l >> 4) * 16;          // byte offset along K
  f32x4 acc[2][4] = {};

  auto STAGE = [&](int buf, int k0) {
    gld_lds16(Ah + ga + k0, (char*)As[buf][0] + dA);
    gld_lds16(bth + gb0 + k0, (char*)Bs[buf][0] + dB0);
    gld_lds16(bth + gb1 + k0, (char*)Bs[buf][0] + dB1);
    if constexpr (SPLIT) {
      gld_lds16(Al + ga + k0, (char*)As[buf][1] + dA);
      gld_lds16(btl + gb0 + k0, (char*)Bs[buf][1] + dB0);
      gld_lds16(btl + gb1 + k0, (char*)Bs[buf][1] + dB1);
    }
  };
  auto COMPUTE = [&](int buf) {
    short8v afh[2], bfh[4];
#pragma unroll
    for (int mi = 0; mi < 2; ++mi)
      afh[mi] = *(const short8v*)((char*)As[buf][0] + (unsigned)(wr + mi * 16 + lrow) * 64 + lk);
#pragma unroll
    for (int ni = 0; ni < 4; ++ni)
      bfh[ni] = *(const short8v*)((char*)Bs[buf][0] + (unsigned)(wc + ni * 16 + lrow) * 64 + lk);
    if constexpr (SPLIT) {
      short8v afl[2], bfl[4];
#pragma unroll
      for (int mi = 0; mi < 2; ++mi)
        afl[mi] = *(const short8v*)((char*)As[buf][1] + (unsigned)(wr + mi * 16 + lrow) * 64 + lk);
#pragma unroll
      for (int ni = 0; ni < 4; ++ni)
        bfl[ni] = *(const short8v*)((char*)Bs[buf][1] + (unsigned)(wc + ni * 16 + lrow) * 64 + lk);
#pragma unroll
      for (int mi = 0; mi < 2; ++mi)
#pragma unroll
        for (int ni = 0; ni < 4; ++ni) {
          acc[mi][ni] = __builtin_amdgcn_mfma_f32_16x16x32_bf16(afh[mi], bfh[ni], acc[mi][ni], 0, 0, 0);
          acc[mi][ni] = __builtin_amdgcn_mfma_f32_16x16x32_bf16(afl[mi], bfh[ni], acc[mi][ni], 0, 0, 0);
          acc[mi][ni] = __builtin_amdgcn_mfma_f32_16x16x32_bf16(afh[mi], bfl[ni], acc[mi][ni], 0, 0, 0);
        }
    } else {
#pragma unroll
      for (int mi = 0; mi < 2; ++mi)
#pragma unroll
        for (int ni = 0; ni < 4; ++ni)
          acc[mi][ni] = __builtin_amdgcn_mfma_f32_16x16x32_bf16(afh[mi], bfh[ni], acc[mi][ni], 0, 0, 0);
    }
  };

  int NT = K / 32;
  if constexpr (NBUF == 2) {
    STAGE(0, 0);
    asm volatile("s_waitcnt vmcnt(0)" ::: "memory");
    __syncthreads();
    int cur = 0;
    for (int t = 0; t < NT; ++t) {
      if (t + 1 < NT) STAGE(cur ^ 1, (t + 1) * 32);
      COMPUTE(cur);
      asm volatile("s_waitcnt vmcnt(0)" ::: "memory");
      __syncthreads();
      cur ^= 1;
    }
  } else {
    // 4-buf: 3 tiles in flight, counted vmcnt (L=3 or 6 loads/STAGE), raw barrier.
    STAGE(0, 0);
    if (NT > 1) STAGE(1, 32);
    if (NT > 2) STAGE(2, 64);
    for (int t = 0; t < NT; ++t) {
      if (t + 2 < NT) {
        if constexpr (SPLIT) asm volatile("s_waitcnt vmcnt(12)" ::: "memory");
        else                 asm volatile("s_waitcnt vmcnt(6)" ::: "memory");
      } else if (t + 1 < NT) {
        if constexpr (SPLIT) asm volatile("s_waitcnt vmcnt(6)" ::: "memory");
        else                 asm volatile("s_waitcnt vmcnt(3)" ::: "memory");
      } else {
        asm volatile("s_waitcnt vmcnt(0)" ::: "memory");
      }
      __builtin_amdgcn_s_barrier();   // all waves' tile-t stages visible; bounds skew
      if (t + 3 < NT) STAGE((t + 3) & 3, (t + 3) * 32);
      COMPUTE(t & 3);
    }
  }

  int lr4 = (l >> 4) << 2;
  if (Cact) {
    // paired-silu epilogue: n even = gate, n odd = up (same logical col n>>1)
#pragma unroll
    for (int mi = 0; mi < 2; ++mi) {
#pragma unroll
      for (int reg = 0; reg < 4; ++reg) {
        int rl = wr + mi * 16 + lr4 + reg;
        int rr = rb + rl;
        bool valid = !(offs && rr >= rows);
        size_t orow = 0;
        if (valid) orow = (size_t)(destb ? destb[base + rr] : (base + rr));
#pragma unroll
        for (int ni = 0; ni < 4; ++ni) {
          float v = acc[mi][ni][reg];
          float other = __shfl_xor(v, 1);
          if (valid && !(l & 1)) {
            float s = 1.f / (1.f + __expf(-v));
            int n = cb + wc + ni * 16 + (l & 15);
            Cact[orow * (size_t)ldact + (n >> 1)] = f2bf(v * s * other);
          }
        }
      }
    }
  } else {
#pragma unroll
    for (int mi = 0; mi < 2; ++mi) {
#pragma unroll
      for (int reg = 0; reg < 4; ++reg) {
        int rl = wr + mi * 16 + lr4 + reg;
        int rr = rb + rl;
        if (offs && rr >= rows) continue;
        size_t orow;
        if (!offs) orow = (size_t)rr;
        else orow = (size_t)(destb ? destb[base + rr] : (base + rr));
        float* crow = C + orow * N + cb + wc + (l & 15);
        const float* arow = Cadd ? (Cadd + orow * N + cb + wc + (l & 15)) : nullptr;
#pragma unroll
        for (int ni = 0; ni < 4; ++ni) {
          float v = acc[mi][ni][reg];
          if (Cadd) v += arow[ni * 16];
          crow[ni * 16] = v;
        }
      }
    }
  }
}

// ---------------- per-head RMS + mROPE, IN-PLACE split-bf16 conversion ----------------
__global__ __launch_bounds__(256) void qknorm_rope(
    float* __restrict__ qkv, const float* __restrict__ scale,
    const int* __restrict__ pos, int H, int coff) {
  int wid = (blockIdx.x * 256 + threadIdx.x) >> 6;
  int lane = threadIdx.x & 63;
  int t = wid / H, hh = wid % H;
  float* row = qkv + (size_t)t * QKVN + coff + hh * 128;
  float v0 = row[lane], v1 = row[lane + 64];
  float ss = v0 * v0 + v1 * v1;
#pragma unroll
  for (int o = 32; o > 0; o >>= 1) ss += __shfl_xor(ss, o);
  float r = rsqrtf(ss / 128.f + EPS);
  float n0 = v0 * r * scale[lane];
  float n1 = v1 * r * scale[lane + 64];
  int axis = lane < 24 ? 0 : (lane < 44 ? 1 : 2);
  float p = (float)pos[axis * T + t];
  float inv = exp2f(-19.931568569324174f * ((float)lane * (1.0f / 64.0f)));
  float f = p * inv;
  float sn, cs;
  sincosf(f, &sn, &cs);
  float o0 = n0 * cs - n1 * sn;
  float o1 = n1 * cs + n0 * sn;
  unsigned short h0 = f2bf(o0), h1 = f2bf(o1);
  unsigned short* o = (unsigned short*)row;
  o[lane] = h0;
  o[lane + 64] = h1;
  o[128 + lane] = f2bf(o0 - bf2f(h0));
  o[192 + lane] = f2bf(o1 - bf2f(h1));
}

// ---------------- MFMA causal GQA flash attention, split-bf16 (3-term) ----------------
// LDS-staged K/V, double-buffered with async prefetch (one barrier per KV tile).
// Lazy defer-max (shuffle tree only when max grows >8), lsum via MFMA-ones,
// fully-masked-tile compute skip, LPT launch order (heavy q-tiles first).
__global__ __launch_bounds__(256) void flash_mfma(
    const char* __restrict__ qkvb, const unsigned short* __restrict__ Vth,
    const unsigned short* __restrict__ Vtl,
    unsigned short* __restrict__ Aoh, unsigned short* __restrict__ Aol) {
  __shared__ alignas(16) unsigned short Ks[2][2][32 * 128];   // [buf][hi/lo][key][d], swizzled
  __shared__ alignas(16) unsigned short Vs[2][2][128 * 32];   // [buf][hi/lo][d][key], swizzled
  __shared__ alignas(16) unsigned short Ps[2][4 * 16 * 32];   // [hi/lo] per-wave [q][key]
  int by = blockIdx.y;
  int b = by >> 5, h = by & 31, kvh = h >> 3;
  int qb0 = (int)(gridDim.x - 1 - blockIdx.x) * 64;   // LPT: heavy blocks first
  int tid = threadIdx.x, w = tid >> 6, l = tid & 63;

  short8v aqh[4], aql[4];
  {
    const char* qrow = qkvb + (size_t)(b * Ss + qb0 + w * 16 + (l & 15)) * 20480
                       + h * 512 + (l >> 4) * 16;
#pragma unroll
    for (int kc = 0; kc < 4; ++kc) {
      aqh[kc] = *(const short8v*)(qrow + kc * 64);
      aql[kc] = *(const short8v*)(qrow + 256 + kc * 64);
    }
  }
  short8v vone;
#pragma unroll
  for (int j = 0; j < 8; ++j) vone[j] = (short)0x3F80;   // bf16 1.0
  f32x4 oacc[8] = {};
  float mrow[4], lsum[4];
#pragma unroll
  for (int r = 0; r < 4; ++r) { mrow[r] = -1e30f; lsum[r] = 0.f; }
  const float sc = 0.08838834764831845f;  // 1/sqrt(128)
  int qgbase = qb0 + w * 16 + ((l >> 4) << 2);
  int ntiles = qb0 / 32 + 2;              // block-uniform (barrier-synced loop)
  int wmaxrow = qb0 + w * 16 + 15;        // this wave's last q row

  auto STAGE = [&](int buf, int kt) {
#pragma unroll
    for (int j = 0; j < 2; ++j) {
      int row = w * 8 + j * 4 + (l >> 4);
      unsigned scol = (unsigned)((l & 15) * 16) ^ ((unsigned)(row & 7) << 4);
      const char* src = qkvb + (size_t)(b * Ss + kt * 32 + row) * 20480
                        + 16384 + kvh * 512 + scol;
      gld_lds16(src, (char*)Ks[buf][0] + (w * 8 + j * 4) * 256);
      gld_lds16(src + 256, (char*)Ks[buf][1] + (w * 8 + j * 4) * 256);
    }
#pragma unroll
    for (int j = 0; j < 2; ++j) {
      int d = w * 32 + j * 16 + (l >> 2);
      unsigned scol = (unsigned)((l & 3) * 16) ^ ((unsigned)(d & 3) << 4);
      size_t vo = (((size_t)(b * HKV + kvh) * 128 + d) * 1024 + kt * 32) * 2 + scol;
      gld_lds16((const char*)Vth + vo, (char*)Vs[buf][0] + (w * 32 + j * 16) * 64);
      gld_lds16((const char*)Vtl + vo, (char*)Vs[buf][1] + (w * 32 + j * 16) * 64);
    }
  };

  STAGE(0, 0);
  asm volatile("s_waitcnt vmcnt(0)" ::: "memory");
  __syncthreads();

  int cur = 0;
  for (int kt = 0; kt < ntiles; ++kt) {
    if (kt + 1 < ntiles) STAGE(cur ^ 1, kt + 1);

    if (kt * 32 <= wmaxrow) {   // wave has at least one unmasked key this tile
      f32x4 s[2] = {};
#pragma unroll
      for (int nt = 0; nt < 2; ++nt) {
        int krow = nt * 16 + (l & 15);
#pragma unroll
        for (int kc = 0; kc < 4; ++kc) {
          unsigned colb = ((unsigned)(kc * 64 + (l >> 4) * 16)) ^ ((unsigned)(krow & 7) << 4);
          short8v bkh = *(const short8v*)((char*)Ks[cur][0] + (unsigned)krow * 256 + colb);
          short8v bkl = *(const short8v*)((char*)Ks[cur][1] + (unsigned)krow * 256 + colb);
          s[nt] = __builtin_amdgcn_mfma_f32_16x16x32_bf16(aqh[kc], bkh, s[nt], 0, 0, 0);
          s[nt] = __builtin_amdgcn_mfma_f32_16x16x32_bf16(aql[kc], bkh, s[nt], 0, 0, 0);
          s[nt] = __builtin_amdgcn_mfma_f32_16x16x32_bf16(aqh[kc], bkl, s[nt], 0, 0, 0);
        }
      }
      // mask + per-lane tile max (no reduction in common path)
      float pv[2][4], tmax[4];
#pragma unroll
      for (int r = 0; r < 4; ++r) tmax[r] = -1e30f;
#pragma unroll
      for (int nt = 0; nt < 2; ++nt) {
        int key = kt * 32 + nt * 16 + (l & 15);
#pragma unroll
        for (int r = 0; r < 4; ++r) {
          float v = s[nt][r] * sc;
          if (key > qgbase + r) v = -1e30f;
          pv[nt][r] = v;
          tmax[r] = fmaxf(tmax[r], v);
        }
      }
      // lazy defer-max: tree + rescale only when some lane's max grew > 8
      bool need = false;
#pragma unroll
      for (int r = 0; r < 4; ++r) need = need || (tmax[r] > mrow[r] + 8.f);
      if (__any(need)) {
#pragma unroll
        for (int o = 1; o < 16; o <<= 1)
#pragma unroll
          for (int r = 0; r < 4; ++r) tmax[r] = fmaxf(tmax[r], __shfl_xor(tmax[r], o));
#pragma unroll
        for (int r = 0; r < 4; ++r) {
          float mn = fmaxf(mrow[r], tmax[r]);
          float corr = __expf(mrow[r] - mn);
          mrow[r] = mn;
          lsum[r] *= corr;
#pragma unroll
          for (int n2 = 0; n2 < 8; ++n2) oacc[n2][r] *= corr;
        }
      }
      // P = exp(S - mrow) (bounded by e^8), split to bf16 hi/lo in LDS
#pragma unroll
      for (int nt = 0; nt < 2; ++nt)
#pragma unroll
        for (int r = 0; r < 4; ++r) {
          float p = __expf(pv[nt][r] - mrow[r]);
          unsigned short ph = f2bf(p);
          unsigned short pl = f2bf(p - bf2f(ph));
          int q = ((l >> 4) << 2) + r;
          int key = nt * 16 + (l & 15);
          unsigned pb = w * 1024 + q * 64 + (((unsigned)key * 2) ^ ((unsigned)(q & 3) << 4));
          *(unsigned short*)((char*)Ps[0] + pb) = ph;
          *(unsigned short*)((char*)Ps[1] + pb) = pl;
        }
      unsigned pr = w * 1024 + (l & 15) * 64 +
                    (((unsigned)(l >> 4) * 16) ^ ((unsigned)(l & 3) << 4));
      short8v pah = *(const short8v*)((char*)Ps[0] + pr);
      short8v pal = *(const short8v*)((char*)Ps[1] + pr);
      // row-sum via MFMA with ones-B: out[q][*] = sum_k P[q][k], layout matches lsum[r]
      {
        f32x4 rs = {};
        rs = __builtin_amdgcn_mfma_f32_16x16x32_bf16(pah, vone, rs, 0, 0, 0);
        rs = __builtin_amdgcn_mfma_f32_16x16x32_bf16(pal, vone, rs, 0, 0, 0);
#pragma unroll
        for (int r = 0; r < 4; ++r) lsum[r] += rs[r];
      }
#pragma unroll
      for (int n2 = 0; n2 < 8; ++n2) {
        int d = n2 * 16 + (l & 15);
        unsigned vb = (unsigned)d * 64 +
                      (((unsigned)(l >> 4) * 16) ^ ((unsigned)(d & 3) << 4));
        short8v bvh = *(const short8v*)((char*)Vs[cur][0] + vb);
        short8v bvl = *(const short8v*)((char*)Vs[cur][1] + vb);
        oacc[n2] = __builtin_amdgcn_mfma_f32_16x16x32_bf16(pah, bvh, oacc[n2], 0, 0, 0);
        oacc[n2] = __builtin_amdgcn_mfma_f32_16x16x32_bf16(pal, bvh, oacc[n2], 0, 0, 0);
        oacc[n2] = __builtin_amdgcn_mfma_f32_16x16x32_bf16(pah, bvl, oacc[n2], 0, 0, 0);
      }
    }
    asm volatile("s_waitcnt vmcnt(0)" ::: "memory");
    __syncthreads();
    cur ^= 1;
  }
#pragma unroll
  for (int r = 0; r < 4; ++r) {
    float inv = 1.f / lsum[r];
    size_t obase = (size_t)(b * Ss + qgbase + r) * 4096 + h * 128 + (l & 15);
#pragma unroll
    for (int n2 = 0; n2 < 8; ++n2) {
      float v = oacc[n2][r] * inv;
      unsigned short hv = f2bf(v);
      Aoh[obase + n2 * 16] = hv;
      Aol[obase + n2 * 16] = f2bf(v - bf2f(hv));
    }
  }
}

// ---------------- router (fp32 h), top-2, counts ----------------
__global__ __launch_bounds__(64) void router_kernel(const float* __restrict__ H,
                                                    const float* __restrict__ RW,
                                                    float* __restrict__ pslot,
                                                    int* __restrict__ topi,
                                                    int* __restrict__ counts) {
  int t = blockIdx.x;
  int lane = threadIdx.x;
  float part[E] = {};
  const float* hrow = H + (size_t)t * Dd;
  for (int d = lane; d < Dd; d += 64) {
    float hv = hrow[d];
    const float* rw = RW + (size_t)d * E;
#pragma unroll
    for (int e = 0; e < E; ++e) part[e] = fmaf(hv, rw[e], part[e]);
  }
#pragma unroll
  for (int e = 0; e < E; ++e)
#pragma unroll
    for (int o = 32; o > 0; o >>= 1) part[e] += __shfl_xor(part[e], o);
  if (lane == 0) {
    float mx = part[0];
#pragma unroll
    for (int e = 1; e < E; ++e) mx = fmaxf(mx, part[e]);
    float p[E];
#pragma unroll
    for (int e = 0; e < E; ++e) p[e] = __expf(part[e] - mx);
    int i0 = 0;
#pragma unroll
    for (int e = 1; e < E; ++e) if (p[e] > p[i0]) i0 = e;
    int i1 = (i0 == 0) ? 1 : 0;
#pragma unroll
    for (int e = 0; e < E; ++e) if (e != i0 && p[e] > p[i1]) i1 = e;
    float p0 = p[i0], p1 = p[i1];
    float denom = p0 + p1;
    pslot[2 * t] = p0 / denom;
    pslot[2 * t + 1] = p1 / denom;
    topi[2 * t] = i0;
    topi[2 * t + 1] = i1;
    atomicAdd(&counts[i0], 1);
    atomicAdd(&counts[i1], 1);
  }
}

__global__ void offsets_kernel(const int* __restrict__ counts, int* __restrict__ offs) {
  if (threadIdx.x == 0) {
    int s = 0;
    for (int e = 0; e < E; ++e) { offs[e] = s; s += counts[e]; }
    offs[E] = s;
  }
}

__global__ __launch_bounds__(256) void scatter_kernel(const int* __restrict__ topi,
                                                      const int* __restrict__ offs,
                                                      int* __restrict__ fill,
                                                      int* __restrict__ gtok,
                                                      int* __restrict__ destb) {
  int t = blockIdx.x * 256 + threadIdx.x;
  if (t >= T) return;
#pragma unroll
  for (int slot = 0; slot < 2; ++slot) {
    int e = topi[2 * t + slot];
    int pos = offs[e] + atomicAdd(&fill[e], 1);
    gtok[pos] = t;
    destb[pos] = 2 * t + slot;
  }
}

// vectorized (float4) weighted combine into residual
__global__ __launch_bounds__(256) void combine_kernel(float* __restrict__ out,
                                                      const float* __restrict__ eo,
                                                      const float* __restrict__ pslot) {
  int g = blockIdx.x * 256 + threadIdx.x;  // < T*Dd/4
  int t = g >> 9;                          // 512 float4 groups per row
  int d4 = g & 511;
  float p0 = pslot[2 * t], p1 = pslot[2 * t + 1];
  const float4 a = *(const float4*)(eo + ((size_t)(2 * t) << 11) + d4 * 4);
  const float4 bq = *(const float4*)(eo + ((size_t)(2 * t + 1) << 11) + d4 * 4);
  float4* o = (float4*)(out + ((size_t)t << 11) + d4 * 4);
  float4 v = *o;
  v.x += p0 * a.x + p1 * bq.x;
  v.y += p0 * a.y + p1 * bq.y;
  v.z += p0 * a.z + p1 * bq.z;
  v.w += p0 * a.w + p1 * bq.w;
  *o = v;
}

}  // namespace

extern "C" void kernel_launch(void* const* d_in, const int* in_sizes, int n_in,
                              void* d_out, int out_size, void* d_ws, size_t ws_size,
                              hipStream_t stream) {
  (void)in_sizes; (void)n_in; (void)out_size; (void)ws_size;
  const float* x = (const float*)d_in[0];
  const int* pos = (const int*)d_in[1];
  const float* pre_s = (const float*)d_in[2];
  const float* wq = (const float*)d_in[3];
  const float* wk = (const float*)d_in[4];
  const float* wv = (const float*)d_in[5];
  const float* wo = (const float*)d_in[6];
  const float* qns = (const float*)d_in[7];
  const float* kns = (const float*)d_in[8];
  const float* post_s = (const float*)d_in[9];
  const float* rw = (const float*)d_in[10];
  const float* gw = (const float*)d_in[11];
  const float* uw = (const float*)d_in[12];
  const float* dw = (const float*)d_in[13];
  float* out = (float*)d_out;
  char* ws = (char*)d_ws;

  // ---- workspace (phase-aliased; MiB offsets; peak ~140 MiB) ----
  unsigned short* hbh = (unsigned short*)(ws + 0);            // [0,8)
  unsigned short* hbl = (unsigned short*)(ws + 8388608);      // [8,16)
  const size_t W0 = 16777216;                                 // [16,64) attn weights
  unsigned short* wqkvTh = (unsigned short*)(ws + W0);
  unsigned short* wqkvTl = (unsigned short*)(ws + W0 + 20971520);
  unsigned short* woTh = (unsigned short*)(ws + W0);          // after QKV gemm
  unsigned short* woTl = (unsigned short*)(ws + W0 + 16777216);
  const size_t X0 = 67108864;                                 // [64,104) qkv / h
  float* qkv = (float*)(ws + X0);
  float* h = (float*)(ws + X0);                               // router input
  const size_t A0 = 109051904;                                // [104,136) attn out
  unsigned short* aoh = (unsigned short*)(ws + A0);
  unsigned short* aol = (unsigned short*)(ws + A0 + 16777216);
  unsigned short* vth = (unsigned short*)(ws + 142606336);    // [136,138)
  unsigned short* vtl = (unsigned short*)(ws + 144703488);    // [138,140)
  // MoE phase (all pre-MoE data dead when each region is written):
  unsigned short* moeGU = (unsigned short*)(ws + 16777216);   // [16,112)  E x 1536 x 2048 bf16 (interleaved gate/up rows)
  unsigned short* actb = (unsigned short*)(ws + 117440512);   // [112,118.3) 4096 x 768 bf16 (GU GEMM epilogue)
  unsigned short* moeD = (unsigned short*)(ws + 16777216);    // [16,64)   E x 2048 x 768 bf16 (after GU GEMM)
  float* eo = (float*)(ws + 67108864);                        // [64,96)   4096 x 2048 fp32 (h dead by then)
  const size_t RT = 146800640;                                // [140,...) router scratch
  float* pslot = (float*)(ws + RT);
  int* topi = (int*)(ws + RT + 16384);
  int* counts = (int*)(ws + RT + 32768);
  int* fill = counts + 16;
  int* offs = fill + 16;
  int* gtok = (int*)(ws + RT + 33280);
  int* destb = gtok + 2 * T;

  // 1. QKV weight transposes (split hi/lo, B^T layout)
  transpose_f32_bf16<<<dim3(128, 64, 1), 256, 0, stream>>>(wq, wqkvTh, wqkvTl, Dd, 4096, 4096, 2048, 0, 0);
  transpose_f32_bf16<<<dim3(16, 64, 1), 256, 0, stream>>>(wk, wqkvTh + (size_t)4096 * 2048, wqkvTl + (size_t)4096 * 2048, Dd, 512, 512, 2048, 0, 0);
  transpose_f32_bf16<<<dim3(16, 64, 1), 256, 0, stream>>>(wv, wqkvTh + (size_t)4608 * 2048, wqkvTl + (size_t)4608 * 2048, Dd, 512, 512, 2048, 0, 0);
  // 2. pre-RMS (split bf16)
  rms_kernel<<<T, 256, 0, stream>>>(x, pre_s, nullptr, hbh, hbl);
  // 3. fused QKV split GEMM -> qkv fp32 (T x 5120); 2-D XCD partition, 2-buf
  gemm_bt<true, 2><<<32 * 40, 256, 0, stream>>>(hbh, hbl, wqkvTh, wqkvTl, nullptr, qkv,
                                                T, QKVN, Dd, 32, 40, 1,
                                                nullptr, nullptr, nullptr, 0, nullptr, 0);
  // 4. qk norm + rope, in-place split-bf16
  qknorm_rope<<<T * HQ / 4, 256, 0, stream>>>(qkv, qns, pos, HQ, 0);
  qknorm_rope<<<T * HKV / 4, 256, 0, stream>>>(qkv, kns, pos, HKV, 4096);
  // 5. V transpose -> vt[b][kvh][d][s] split bf16
  for (int b = 0; b < Bb; ++b)
    transpose_f32_bf16<<<dim3(4, 32, HKV), 256, 0, stream>>>(
        qkv + (size_t)b * Ss * QKVN + 4608, vth + (size_t)b * HKV * 131072,
        vtl + (size_t)b * HKV * 131072, Ss, HD, QKVN, Ss, 128, 131072);
  // 6. wo transpose (split) into W region (wqkvT dead)
  transpose_f32_bf16<<<dim3(64, 128, 1), 256, 0, stream>>>(wo, woTh, woTl, 4096, Dd, 2048, 4096, 0, 0);
  // 7. split MFMA flash attention (LDS dbuf prefetch) -> ao hi/lo
  flash_mfma<<<dim3(Ss / 64, Bb * HQ), 256, 0, stream>>>((const char*)(ws + X0), vth, vtl, aoh, aol);
  // 8. O-proj split GEMM + residual -> out fp32; 2-D XCD partition, 2-buf
  gemm_bt<true, 2><<<32 * 16, 256, 0, stream>>>(aoh, aol, woTh, woTl, x, out,
                                                T, Dd, HQ * HD, 32, 16, 1,
                                                nullptr, nullptr, nullptr, 0, nullptr, 0);
  // 9. post-RMS (fp32 h for router + plain bf16 for experts)
  rms_kernel<<<T, 256, 0, stream>>>(out, post_s, h, hbh, nullptr);
  // 10. router + expert grouping
  hipMemsetAsync(counts, 0, 2 * E * sizeof(int), stream);
  router_kernel<<<T, 64, 0, stream>>>(h, rw, pslot, topi, counts);
  offsets_kernel<<<1, 64, 0, stream>>>(counts, offs);
  scatter_kernel<<<T / 256, 256, 0, stream>>>(topi, offs, fill, gtok, destb);
  // 11. MoE: gate/up transposed INTERLEAVED (gate col j -> row 2j, up -> 2j+1)
  transpose_f32_bf16<<<dim3(24, 64, E), 256, 0, stream>>>(gw, moeGU, nullptr, Dd, I, I, 4096,
                                                          (long)Dd * I, (long)1536 * 2048);
  transpose_f32_bf16<<<dim3(24, 64, E), 256, 0, stream>>>(uw, moeGU + 2048, nullptr, Dd, I, I, 4096,
                                                          (long)Dd * I, (long)1536 * 2048);
  // 12. ONE grouped GEMM with fused silu epilogue -> actb bf16 (4-buf, expert-pinned XCDs)
  gemm_bt<false, 4><<<32 * 12 * E, 256, 0, stream>>>(hbh, nullptr, moeGU, nullptr, nullptr, nullptr,
                                                     0, 1536, Dd, 32, 12, E,
                                                     gtok, nullptr, offs, (long)1536 * 2048,
                                                     actb, I);
  // 13. down: transpose then grouped GEMM (4-buf, expert-pinned XCDs), scatter rows
  transpose_f32_bf16<<<dim3(64, 24, E), 256, 0, stream>>>(dw, moeD, nullptr, I, Dd, Dd, I,
                                                          (long)I * Dd, (long)Dd * I);
  gemm_bt<false, 4><<<32 * 16 * E, 256, 0, stream>>>(actb, nullptr, moeD, nullptr, nullptr, eo,
                                                     0, Dd, I, 32, 16, E,
                                                     nullptr, destb, offs, (long)Dd * I,
                                                     nullptr, 0);
  // 14. weighted combine into residual (float4)
  combine_kernel<<<(T * Dd / 4) / 256, 256, 0, stream>>>(out, eo, pslot);
}

// Round 17
// 763.166 us; speedup vs baseline: 1.0296x; 1.0179x over previous
//
#include <hip/hip_runtime.h>
#include <math.h>

namespace {

constexpr int Bb = 2, Ss = 1024, Dd = 2048;
constexpr int HQ = 32, HKV = 4, HD = 128;
constexpr int E = 16, I = 768;
constexpr int T = Bb * Ss;                 // 2048 tokens
constexpr int QKVN = HQ * HD + 2 * HKV * HD;  // 5120
constexpr float EPS = 1e-6f;

typedef __attribute__((ext_vector_type(8))) short short8v;
typedef __attribute__((ext_vector_type(4))) float f32x4;

__device__ __forceinline__ unsigned short f2bf(float f) {
  unsigned u = __float_as_uint(f);
  u += 0x7fffu + ((u >> 16) & 1u);   // RNE
  return (unsigned short)(u >> 16);
}
__device__ __forceinline__ float bf2f(unsigned short h) {
  return __uint_as_float((unsigned)h << 16);
}

// global(16B per lane) -> LDS direct; lds_dst must be wave-uniform.
__device__ __forceinline__ void gld_lds16(const void* gsrc, void* lds_dst) {
  __builtin_amdgcn_global_load_lds(
      (const __attribute__((address_space(1))) void*)(unsigned long long)gsrc,
      (__attribute__((address_space(3))) void*)(unsigned)(unsigned long long)lds_dst,
      16, 0, 0);
}

// ---------------- RMS norm over D=2048; fp32 / bf16-hi / bf16-lo outputs ----------------
__global__ __launch_bounds__(256) void rms_kernel(const float* __restrict__ x,
                                                  const float* __restrict__ scale,
                                                  float* __restrict__ outf,
                                                  unsigned short* __restrict__ outh,
                                                  unsigned short* __restrict__ outl) {
  int row = blockIdx.x;
  const float* xr = x + (size_t)row * Dd;
  float ss = 0.f;
  for (int i = threadIdx.x; i < Dd; i += 256) { float v = xr[i]; ss += v * v; }
#pragma unroll
  for (int o = 32; o > 0; o >>= 1) ss += __shfl_xor(ss, o);
  __shared__ float red[4];
  int wave = threadIdx.x >> 6, lane = threadIdx.x & 63;
  if (lane == 0) red[wave] = ss;
  __syncthreads();
  __shared__ float s_r;
  if (threadIdx.x == 0) {
    float tot = red[0] + red[1] + red[2] + red[3];
    s_r = rsqrtf(tot / (float)Dd + EPS);
  }
  __syncthreads();
  float r = s_r;
  for (int i = threadIdx.x; i < Dd; i += 256) {
    float v = xr[i] * r * scale[i];
    if (outf) outf[(size_t)row * Dd + i] = v;
    if (outh) {
      unsigned short hv = f2bf(v);
      outh[(size_t)row * Dd + i] = hv;
      if (outl) outl[(size_t)row * Dd + i] = f2bf(v - bf2f(hv));
    }
  }
}

// ---------------- tiled fp32 -> bf16(hi[,lo]) transpose: out[C][R] = in[R][C] ----------------
__global__ __launch_bounds__(256) void transpose_f32_bf16(
    const float* __restrict__ in, unsigned short* __restrict__ outh,
    unsigned short* __restrict__ outl,
    int R, int C, long in_rs, long out_rs, long in_bs, long out_bs) {
  __shared__ float tile[32][33];
  const float* inb = in + (size_t)blockIdx.z * in_bs;
  int r0 = blockIdx.y * 32, c0 = blockIdx.x * 32;
  int tx = threadIdx.x & 31, ty = threadIdx.x >> 5;  // ty 0..7
#pragma unroll
  for (int i = 0; i < 32; i += 8)
    tile[ty + i][tx] = inb[(size_t)(r0 + ty + i) * in_rs + c0 + tx];
  __syncthreads();
#pragma unroll
  for (int i = 0; i < 32; i += 8) {
    float v = tile[tx][ty + i];
    unsigned short hv = f2bf(v);
    size_t oidx = (size_t)blockIdx.z * out_bs + (size_t)(c0 + ty + i) * out_rs + r0 + tx;
    outh[oidx] = hv;
    if (outl) outl[oidx] = f2bf(v - bf2f(hv));
  }
}

// ---------------- bf16 MFMA GEMM, 64x128 tile ----------------
// C = A(MxK) * BT(NxK)^T (+Cadd). SPLIT: 3-term hi/lo (~fp32 precision).
// NBUF=2: dbuf prefetch (drain) — best for split (48 KB LDS, 2+ blocks/CU).
// NBUF=4: counted-vmcnt pipeline (3 tiles in flight) + T5 setprio — non-split MoE.
// 1-D launch, XCD-aware decode:
//   dense (nE==1): 2-D partition — each XCD owns an (M/2 x N/4) rectangle.
//   MoE  (nE>1):  ALL blocks of expert e land on XCD e&7.
// MoE mode via offs/gtok/destb. Cact!=null: paired-silu epilogue.
template <bool SPLIT, int NBUF>
__global__ __launch_bounds__(256) void gemm_bt(
    const unsigned short* __restrict__ Ah, const unsigned short* __restrict__ Al,
    const unsigned short* __restrict__ Bh, const unsigned short* __restrict__ Bl,
    const float* __restrict__ Cadd, float* __restrict__ C,
    int M, int N, int K, int nMb, int nNb, int nE,
    const int* __restrict__ gtok, const int* __restrict__ destb,
    const int* __restrict__ offs, long bt_estride,
    unsigned short* __restrict__ Cact, int ldact) {
  constexpr int NP = SPLIT ? 2 : 1;
  __shared__ alignas(16) unsigned short As[NBUF][NP][64 * 32];
  __shared__ alignas(16) unsigned short Bs[NBUF][NP][128 * 32];
  int bid = blockIdx.x;
  int xcd = bid & 7, rest = bid >> 3;
  int mIdx, nIdx, eIdx;
  if (nE > 1) {
    // expert-major: expert e pinned to XCD e&7 (nE % 8 == 0)
    int gpe = nMb * nNb;                  // blocks per expert
    eIdx = xcd + 8 * (rest / gpe);
    int rem = rest % gpe;
    mIdx = rem % nMb;
    nIdx = rem / nMb;
    if (eIdx >= nE) return;
  } else {
    // dense 2-D: xcd = mh*4 + nq; rest = lm + (nMb/2)*ln  (nMb%2==0, nNb%4==0)
    int nMh = nMb >> 1, nNq = nNb >> 2;
    int mh = xcd >> 2, nq = xcd & 3;
    int lm = rest % nMh, ln = rest / nMh;
    if (ln >= nNq) return;
    mIdx = mh * nMh + lm;
    nIdx = nq * nNq + ln;
    eIdx = 0;
  }

  int base = 0, rows = M;
  const unsigned short* bth = Bh;
  const unsigned short* btl = Bl;
  if (offs) {
    base = offs[eIdx];
    rows = offs[eIdx + 1] - base;
    bth = Bh + (size_t)eIdx * bt_estride;
    if (SPLIT) btl = Bl + (size_t)eIdx * bt_estride;
  }
  int rb = mIdx * 64;
  if (rb >= rows) return;
  int cb = nIdx * 128;
  int tid = threadIdx.x, w = tid >> 6, l = tid & 63;

  // A staging: one row per thread. row = w*16 + (l>>2), k-chunk (l&3)*8.
  size_t ga;
  {
    int ra = rb + w * 16 + (l >> 2);
    if (ra >= rows) ra = rows - 1;
    int gg = offs ? (gtok ? gtok[base + ra] : (base + ra)) : ra;
    ga = (size_t)gg * K + (l & 3) * 8;
  }
  // B staging: two rows per thread: w*32 + j*16 + (l>>2).
  size_t gb0 = (size_t)(cb + w * 32 + (l >> 2)) * K + (l & 3) * 8;
  size_t gb1 = gb0 + (size_t)16 * K;
  unsigned dA = (unsigned)w * 1024;               // LDS byte offsets (wave-uniform)
  unsigned dB0 = (unsigned)w * 2048;
  unsigned dB1 = dB0 + 1024;

  int wr = (w >> 1) * 32, wc = (w & 1) * 64;
  int lrow = l & 15;
  unsigned lk = (unsigned)(l >> 4) * 16;          // byte offset along K
  f32x4 acc[2][4] = {};

  auto STAGE = [&](int buf, int k0) {
    gld_lds16(Ah + ga + k0, (char*)As[buf][0] + dA);
    gld_lds16(bth + gb0 + k0, (char*)Bs[buf][0] + dB0);
    gld_lds16(bth + gb1 + k0, (char*)Bs[buf][0] + dB1);
    if constexpr (SPLIT) {
      gld_lds16(Al + ga + k0, (char*)As[buf][1] + dA);
      gld_lds16(btl + gb0 + k0, (char*)Bs[buf][1] + dB0);
      gld_lds16(btl + gb1 + k0, (char*)Bs[buf][1] + dB1);
    }
  };
  auto COMPUTE = [&](int buf) {
    short8v afh[2], bfh[4];
#pragma unroll
    for (int mi = 0; mi < 2; ++mi)
      afh[mi] = *(const short8v*)((char*)As[buf][0] + (unsigned)(wr + mi * 16 + lrow) * 64 + lk);
#pragma unroll
    for (int ni = 0; ni < 4; ++ni)
      bfh[ni] = *(const short8v*)((char*)Bs[buf][0] + (unsigned)(wc + ni * 16 + lrow) * 64 + lk);
    if constexpr (SPLIT) {
      short8v afl[2], bfl[4];
#pragma unroll
      for (int mi = 0; mi < 2; ++mi)
        afl[mi] = *(const short8v*)((char*)As[buf][1] + (unsigned)(wr + mi * 16 + lrow) * 64 + lk);
#pragma unroll
      for (int ni = 0; ni < 4; ++ni)
        bfl[ni] = *(const short8v*)((char*)Bs[buf][1] + (unsigned)(wc + ni * 16 + lrow) * 64 + lk);
#pragma unroll
      for (int mi = 0; mi < 2; ++mi)
#pragma unroll
        for (int ni = 0; ni < 4; ++ni) {
          acc[mi][ni] = __builtin_amdgcn_mfma_f32_16x16x32_bf16(afh[mi], bfh[ni], acc[mi][ni], 0, 0, 0);
          acc[mi][ni] = __builtin_amdgcn_mfma_f32_16x16x32_bf16(afl[mi], bfh[ni], acc[mi][ni], 0, 0, 0);
          acc[mi][ni] = __builtin_amdgcn_mfma_f32_16x16x32_bf16(afh[mi], bfl[ni], acc[mi][ni], 0, 0, 0);
        }
    } else {
#pragma unroll
      for (int mi = 0; mi < 2; ++mi)
#pragma unroll
        for (int ni = 0; ni < 4; ++ni)
          acc[mi][ni] = __builtin_amdgcn_mfma_f32_16x16x32_bf16(afh[mi], bfh[ni], acc[mi][ni], 0, 0, 0);
    }
  };

  int NT = K / 32;
  if constexpr (NBUF == 2) {
    STAGE(0, 0);
    asm volatile("s_waitcnt vmcnt(0)" ::: "memory");
    __syncthreads();
    int cur = 0;
    for (int t = 0; t < NT; ++t) {
      if (t + 1 < NT) STAGE(cur ^ 1, (t + 1) * 32);
      COMPUTE(cur);
      asm volatile("s_waitcnt vmcnt(0)" ::: "memory");
      __syncthreads();
      cur ^= 1;
    }
  } else {
    // 4-buf: 3 tiles in flight, counted vmcnt (L=3 or 6 loads/STAGE), raw barrier.
    // T5: setprio(1) around the MFMA cluster — pays on role-split schedules.
    STAGE(0, 0);
    if (NT > 1) STAGE(1, 32);
    if (NT > 2) STAGE(2, 64);
    for (int t = 0; t < NT; ++t) {
      if (t + 2 < NT) {
        if constexpr (SPLIT) asm volatile("s_waitcnt vmcnt(12)" ::: "memory");
        else                 asm volatile("s_waitcnt vmcnt(6)" ::: "memory");
      } else if (t + 1 < NT) {
        if constexpr (SPLIT) asm volatile("s_waitcnt vmcnt(6)" ::: "memory");
        else                 asm volatile("s_waitcnt vmcnt(3)" ::: "memory");
      } else {
        asm volatile("s_waitcnt vmcnt(0)" ::: "memory");
      }
      __builtin_amdgcn_s_barrier();   // all waves' tile-t stages visible; bounds skew
      if (t + 3 < NT) STAGE((t + 3) & 3, (t + 3) * 32);
      __builtin_amdgcn_s_setprio(1);
      COMPUTE(t & 3);
      __builtin_amdgcn_s_setprio(0);
    }
  }

  int lr4 = (l >> 4) << 2;
  if (Cact) {
    // paired-silu epilogue: n even = gate, n odd = up (same logical col n>>1)
#pragma unroll
    for (int mi = 0; mi < 2; ++mi) {
#pragma unroll
      for (int reg = 0; reg < 4; ++reg) {
        int rl = wr + mi * 16 + lr4 + reg;
        int rr = rb + rl;
        bool valid = !(offs && rr >= rows);
        size_t orow = 0;
        if (valid) orow = (size_t)(destb ? destb[base + rr] : (base + rr));
#pragma unroll
        for (int ni = 0; ni < 4; ++ni) {
          float v = acc[mi][ni][reg];
          float other = __shfl_xor(v, 1);
          if (valid && !(l & 1)) {
            float s = 1.f / (1.f + __expf(-v));
            int n = cb + wc + ni * 16 + (l & 15);
            Cact[orow * (size_t)ldact + (n >> 1)] = f2bf(v * s * other);
          }
        }
      }
    }
  } else {
#pragma unroll
    for (int mi = 0; mi < 2; ++mi) {
#pragma unroll
      for (int reg = 0; reg < 4; ++reg) {
        int rl = wr + mi * 16 + lr4 + reg;
        int rr = rb + rl;
        if (offs && rr >= rows) continue;
        size_t orow;
        if (!offs) orow = (size_t)rr;
        else orow = (size_t)(destb ? destb[base + rr] : (base + rr));
        float* crow = C + orow * N + cb + wc + (l & 15);
        const float* arow = Cadd ? (Cadd + orow * N + cb + wc + (l & 15)) : nullptr;
#pragma unroll
        for (int ni = 0; ni < 4; ++ni) {
          float v = acc[mi][ni][reg];
          if (Cadd) v += arow[ni * 16];
          crow[ni * 16] = v;
        }
      }
    }
  }
}

// ---------------- per-head RMS + mROPE, IN-PLACE split-bf16 conversion ----------------
__global__ __launch_bounds__(256) void qknorm_rope(
    float* __restrict__ qkv, const float* __restrict__ scale,
    const int* __restrict__ pos, int H, int coff) {
  int wid = (blockIdx.x * 256 + threadIdx.x) >> 6;
  int lane = threadIdx.x & 63;
  int t = wid / H, hh = wid % H;
  float* row = qkv + (size_t)t * QKVN + coff + hh * 128;
  float v0 = row[lane], v1 = row[lane + 64];
  float ss = v0 * v0 + v1 * v1;
#pragma unroll
  for (int o = 32; o > 0; o >>= 1) ss += __shfl_xor(ss, o);
  float r = rsqrtf(ss / 128.f + EPS);
  float n0 = v0 * r * scale[lane];
  float n1 = v1 * r * scale[lane + 64];
  int axis = lane < 24 ? 0 : (lane < 44 ? 1 : 2);
  float p = (float)pos[axis * T + t];
  float inv = exp2f(-19.931568569324174f * ((float)lane * (1.0f / 64.0f)));
  float f = p * inv;
  float sn, cs;
  sincosf(f, &sn, &cs);
  float o0 = n0 * cs - n1 * sn;
  float o1 = n1 * cs + n0 * sn;
  unsigned short h0 = f2bf(o0), h1 = f2bf(o1);
  unsigned short* o = (unsigned short*)row;
  o[lane] = h0;
  o[lane + 64] = h1;
  o[128 + lane] = f2bf(o0 - bf2f(h0));
  o[192 + lane] = f2bf(o1 - bf2f(h1));
}

// ---------------- MFMA causal GQA flash attention, split-bf16 (3-term) ----------------
// LDS-staged K/V, double-buffered with async prefetch (one barrier per KV tile).
// Lazy defer-max (shuffle tree only when max grows >8), lsum via MFMA-ones,
// fully-masked-tile compute skip, LPT launch order (heavy q-tiles first).
__global__ __launch_bounds__(256) void flash_mfma(
    const char* __restrict__ qkvb, const unsigned short* __restrict__ Vth,
    const unsigned short* __restrict__ Vtl,
    unsigned short* __restrict__ Aoh, unsigned short* __restrict__ Aol) {
  __shared__ alignas(16) unsigned short Ks[2][2][32 * 128];   // [buf][hi/lo][key][d], swizzled
  __shared__ alignas(16) unsigned short Vs[2][2][128 * 32];   // [buf][hi/lo][d][key], swizzled
  __shared__ alignas(16) unsigned short Ps[2][4 * 16 * 32];   // [hi/lo] per-wave [q][key]
  int by = blockIdx.y;
  int b = by >> 5, h = by & 31, kvh = h >> 3;
  int qb0 = (int)(gridDim.x - 1 - blockIdx.x) * 64;   // LPT: heavy blocks first
  int tid = threadIdx.x, w = tid >> 6, l = tid & 63;

  short8v aqh[4], aql[4];
  {
    const char* qrow = qkvb + (size_t)(b * Ss + qb0 + w * 16 + (l & 15)) * 20480
                       + h * 512 + (l >> 4) * 16;
#pragma unroll
    for (int kc = 0; kc < 4; ++kc) {
      aqh[kc] = *(const short8v*)(qrow + kc * 64);
      aql[kc] = *(const short8v*)(qrow + 256 + kc * 64);
    }
  }
  short8v vone;
#pragma unroll
  for (int j = 0; j < 8; ++j) vone[j] = (short)0x3F80;   // bf16 1.0
  f32x4 oacc[8] = {};
  float mrow[4], lsum[4];
#pragma unroll
  for (int r = 0; r < 4; ++r) { mrow[r] = -1e30f; lsum[r] = 0.f; }
  const float sc = 0.08838834764831845f;  // 1/sqrt(128)
  int qgbase = qb0 + w * 16 + ((l >> 4) << 2);
  int ntiles = qb0 / 32 + 2;              // block-uniform (barrier-synced loop)
  int wmaxrow = qb0 + w * 16 + 15;        // this wave's last q row

  auto STAGE = [&](int buf, int kt) {
#pragma unroll
    for (int j = 0; j < 2; ++j) {
      int row = w * 8 + j * 4 + (l >> 4);
      unsigned scol = (unsigned)((l & 15) * 16) ^ ((unsigned)(row & 7) << 4);
      const char* src = qkvb + (size_t)(b * Ss + kt * 32 + row) * 20480
                        + 16384 + kvh * 512 + scol;
      gld_lds16(src, (char*)Ks[buf][0] + (w * 8 + j * 4) * 256);
      gld_lds16(src + 256, (char*)Ks[buf][1] + (w * 8 + j * 4) * 256);
    }
#pragma unroll
    for (int j = 0; j < 2; ++j) {
      int d = w * 32 + j * 16 + (l >> 2);
      unsigned scol = (unsigned)((l & 3) * 16) ^ ((unsigned)(d & 3) << 4);
      size_t vo = (((size_t)(b * HKV + kvh) * 128 + d) * 1024 + kt * 32) * 2 + scol;
      gld_lds16((const char*)Vth + vo, (char*)Vs[buf][0] + (w * 32 + j * 16) * 64);
      gld_lds16((const char*)Vtl + vo, (char*)Vs[buf][1] + (w * 32 + j * 16) * 64);
    }
  };

  STAGE(0, 0);
  asm volatile("s_waitcnt vmcnt(0)" ::: "memory");
  __syncthreads();

  int cur = 0;
  for (int kt = 0; kt < ntiles; ++kt) {
    if (kt + 1 < ntiles) STAGE(cur ^ 1, kt + 1);

    if (kt * 32 <= wmaxrow) {   // wave has at least one unmasked key this tile
      f32x4 s[2] = {};
#pragma unroll
      for (int nt = 0; nt < 2; ++nt) {
        int krow = nt * 16 + (l & 15);
#pragma unroll
        for (int kc = 0; kc < 4; ++kc) {
          unsigned colb = ((unsigned)(kc * 64 + (l >> 4) * 16)) ^ ((unsigned)(krow & 7) << 4);
          short8v bkh = *(const short8v*)((char*)Ks[cur][0] + (unsigned)krow * 256 + colb);
          short8v bkl = *(const short8v*)((char*)Ks[cur][1] + (unsigned)krow * 256 + colb);
          s[nt] = __builtin_amdgcn_mfma_f32_16x16x32_bf16(aqh[kc], bkh, s[nt], 0, 0, 0);
          s[nt] = __builtin_amdgcn_mfma_f32_16x16x32_bf16(aql[kc], bkh, s[nt], 0, 0, 0);
          s[nt] = __builtin_amdgcn_mfma_f32_16x16x32_bf16(aqh[kc], bkl, s[nt], 0, 0, 0);
        }
      }
      // mask + per-lane tile max (no reduction in common path)
      float pv[2][4], tmax[4];
#pragma unroll
      for (int r = 0; r < 4; ++r) tmax[r] = -1e30f;
#pragma unroll
      for (int nt = 0; nt < 2; ++nt) {
        int key = kt * 32 + nt * 16 + (l & 15);
#pragma unroll
        for (int r = 0; r < 4; ++r) {
          float v = s[nt][r] * sc;
          if (key > qgbase + r) v = -1e30f;
          pv[nt][r] = v;
          tmax[r] = fmaxf(tmax[r], v);
        }
      }
      // lazy defer-max: tree + rescale only when some lane's max grew > 8
      bool need = false;
#pragma unroll
      for (int r = 0; r < 4; ++r) need = need || (tmax[r] > mrow[r] + 8.f);
      if (__any(need)) {
#pragma unroll
        for (int o = 1; o < 16; o <<= 1)
#pragma unroll
          for (int r = 0; r < 4; ++r) tmax[r] = fmaxf(tmax[r], __shfl_xor(tmax[r], o));
#pragma unroll
        for (int r = 0; r < 4; ++r) {
          float mn = fmaxf(mrow[r], tmax[r]);
          float corr = __expf(mrow[r] - mn);
          mrow[r] = mn;
          lsum[r] *= corr;
#pragma unroll
          for (int n2 = 0; n2 < 8; ++n2) oacc[n2][r] *= corr;
        }
      }
      // P = exp(S - mrow) (bounded by e^8), split to bf16 hi/lo in LDS
#pragma unroll
      for (int nt = 0; nt < 2; ++nt)
#pragma unroll
        for (int r = 0; r < 4; ++r) {
          float p = __expf(pv[nt][r] - mrow[r]);
          unsigned short ph = f2bf(p);
          unsigned short pl = f2bf(p - bf2f(ph));
          int q = ((l >> 4) << 2) + r;
          int key = nt * 16 + (l & 15);
          unsigned pb = w * 1024 + q * 64 + (((unsigned)key * 2) ^ ((unsigned)(q & 3) << 4));
          *(unsigned short*)((char*)Ps[0] + pb) = ph;
          *(unsigned short*)((char*)Ps[1] + pb) = pl;
        }
      unsigned pr = w * 1024 + (l & 15) * 64 +
                    (((unsigned)(l >> 4) * 16) ^ ((unsigned)(l & 3) << 4));
      short8v pah = *(const short8v*)((char*)Ps[0] + pr);
      short8v pal = *(const short8v*)((char*)Ps[1] + pr);
      // row-sum via MFMA with ones-B: out[q][*] = sum_k P[q][k], layout matches lsum[r]
      {
        f32x4 rs = {};
        rs = __builtin_amdgcn_mfma_f32_16x16x32_bf16(pah, vone, rs, 0, 0, 0);
        rs = __builtin_amdgcn_mfma_f32_16x16x32_bf16(pal, vone, rs, 0, 0, 0);
#pragma unroll
        for (int r = 0; r < 4; ++r) lsum[r] += rs[r];
      }
#pragma unroll
      for (int n2 = 0; n2 < 8; ++n2) {
        int d = n2 * 16 + (l & 15);
        unsigned vb = (unsigned)d * 64 +
                      (((unsigned)(l >> 4) * 16) ^ ((unsigned)(d & 3) << 4));
        short8v bvh = *(const short8v*)((char*)Vs[cur][0] + vb);
        short8v bvl = *(const short8v*)((char*)Vs[cur][1] + vb);
        oacc[n2] = __builtin_amdgcn_mfma_f32_16x16x32_bf16(pah, bvh, oacc[n2], 0, 0, 0);
        oacc[n2] = __builtin_amdgcn_mfma_f32_16x16x32_bf16(pal, bvh, oacc[n2], 0, 0, 0);
        oacc[n2] = __builtin_amdgcn_mfma_f32_16x16x32_bf16(pah, bvl, oacc[n2], 0, 0, 0);
      }
    }
    asm volatile("s_waitcnt vmcnt(0)" ::: "memory");
    __syncthreads();
    cur ^= 1;
  }
#pragma unroll
  for (int r = 0; r < 4; ++r) {
    float inv = 1.f / lsum[r];
    size_t obase = (size_t)(b * Ss + qgbase + r) * 4096 + h * 128 + (l & 15);
#pragma unroll
    for (int n2 = 0; n2 < 8; ++n2) {
      float v = oacc[n2][r] * inv;
      unsigned short hv = f2bf(v);
      Aoh[obase + n2 * 16] = hv;
      Aol[obase + n2 * 16] = f2bf(v - bf2f(hv));
    }
  }
}

// ---------------- router: fused RMS (identical reduction to rms_kernel) + top-2 ----------------
__global__ __launch_bounds__(256) void router_kernel(const float* __restrict__ X,
                                                     const float* __restrict__ scale,
                                                     const float* __restrict__ RW,
                                                     float* __restrict__ pslot,
                                                     int* __restrict__ topi,
                                                     int* __restrict__ counts) {
  int t = blockIdx.x;
  const float* xr = X + (size_t)t * Dd;
  float ss = 0.f;
  for (int i = threadIdx.x; i < Dd; i += 256) { float v = xr[i]; ss += v * v; }
#pragma unroll
  for (int o = 32; o > 0; o >>= 1) ss += __shfl_xor(ss, o);
  __shared__ float red[4];
  int wave = threadIdx.x >> 6, lane = threadIdx.x & 63;
  if (lane == 0) red[wave] = ss;
  __syncthreads();
  __shared__ float s_r;
  if (threadIdx.x == 0) {
    float tot = red[0] + red[1] + red[2] + red[3];
    s_r = rsqrtf(tot / (float)Dd + EPS);
  }
  __syncthreads();
  float r = s_r;
  float part[E] = {};
  for (int i = threadIdx.x; i < Dd; i += 256) {
    float hv = xr[i] * r * scale[i];
    const float* rwp = RW + (size_t)i * E;
#pragma unroll
    for (int e = 0; e < E; ++e) part[e] = fmaf(hv, rwp[e], part[e]);
  }
#pragma unroll
  for (int e = 0; e < E; ++e)
#pragma unroll
    for (int o = 32; o > 0; o >>= 1) part[e] += __shfl_xor(part[e], o);
  __shared__ float pr[4][E];
  if (lane == 0)
#pragma unroll
    for (int e = 0; e < E; ++e) pr[wave][e] = part[e];
  __syncthreads();
  if (threadIdx.x == 0) {
    float lg[E];
#pragma unroll
    for (int e = 0; e < E; ++e) lg[e] = pr[0][e] + pr[1][e] + pr[2][e] + pr[3][e];
    float mx = lg[0];
#pragma unroll
    for (int e = 1; e < E; ++e) mx = fmaxf(mx, lg[e]);
    float p[E];
#pragma unroll
    for (int e = 0; e < E; ++e) p[e] = __expf(lg[e] - mx);
    int i0 = 0;
#pragma unroll
    for (int e = 1; e < E; ++e) if (p[e] > p[i0]) i0 = e;
    int i1 = (i0 == 0) ? 1 : 0;
#pragma unroll
    for (int e = 0; e < E; ++e) if (e != i0 && p[e] > p[i1]) i1 = e;
    float p0 = p[i0], p1 = p[i1];
    float denom = p0 + p1;
    pslot[2 * t] = p0 / denom;
    pslot[2 * t + 1] = p1 / denom;
    topi[2 * t] = i0;
    topi[2 * t + 1] = i1;
    atomicAdd(&counts[i0], 1);
    atomicAdd(&counts[i1], 1);
  }
}

__global__ void offsets_kernel(const int* __restrict__ counts, int* __restrict__ offs) {
  if (threadIdx.x == 0) {
    int s = 0;
    for (int e = 0; e < E; ++e) { offs[e] = s; s += counts[e]; }
    offs[E] = s;
  }
}

__global__ __launch_bounds__(256) void scatter_kernel(const int* __restrict__ topi,
                                                      const int* __restrict__ offs,
                                                      int* __restrict__ fill,
                                                      int* __restrict__ gtok,
                                                      int* __restrict__ destb) {
  int t = blockIdx.x * 256 + threadIdx.x;
  if (t >= T) return;
#pragma unroll
  for (int slot = 0; slot < 2; ++slot) {
    int e = topi[2 * t + slot];
    int pos = offs[e] + atomicAdd(&fill[e], 1);
    gtok[pos] = t;
    destb[pos] = 2 * t + slot;
  }
}

// vectorized (float4) weighted combine into residual
__global__ __launch_bounds__(256) void combine_kernel(float* __restrict__ out,
                                                      const float* __restrict__ eo,
                                                      const float* __restrict__ pslot) {
  int g = blockIdx.x * 256 + threadIdx.x;  // < T*Dd/4
  int t = g >> 9;                          // 512 float4 groups per row
  int d4 = g & 511;
  float p0 = pslot[2 * t], p1 = pslot[2 * t + 1];
  const float4 a = *(const float4*)(eo + ((size_t)(2 * t) << 11) + d4 * 4);
  const float4 bq = *(const float4*)(eo + ((size_t)(2 * t + 1) << 11) + d4 * 4);
  float4* o = (float4*)(out + ((size_t)t << 11) + d4 * 4);
  float4 v = *o;
  v.x += p0 * a.x + p1 * bq.x;
  v.y += p0 * a.y + p1 * bq.y;
  v.z += p0 * a.z + p1 * bq.z;
  v.w += p0 * a.w + p1 * bq.w;
  *o = v;
}

}  // namespace

extern "C" void kernel_launch(void* const* d_in, const int* in_sizes, int n_in,
                              void* d_out, int out_size, void* d_ws, size_t ws_size,
                              hipStream_t stream) {
  (void)in_sizes; (void)n_in; (void)out_size; (void)ws_size;
  const float* x = (const float*)d_in[0];
  const int* pos = (const int*)d_in[1];
  const float* pre_s = (const float*)d_in[2];
  const float* wq = (const float*)d_in[3];
  const float* wk = (const float*)d_in[4];
  const float* wv = (const float*)d_in[5];
  const float* wo = (const float*)d_in[6];
  const float* qns = (const float*)d_in[7];
  const float* kns = (const float*)d_in[8];
  const float* post_s = (const float*)d_in[9];
  const float* rw = (const float*)d_in[10];
  const float* gw = (const float*)d_in[11];
  const float* uw = (const float*)d_in[12];
  const float* dw = (const float*)d_in[13];
  float* out = (float*)d_out;
  char* ws = (char*)d_ws;

  // ---- workspace (phase-aliased; MiB offsets; peak ~140 MiB) ----
  unsigned short* hbh = (unsigned short*)(ws + 0);            // [0,8)
  unsigned short* hbl = (unsigned short*)(ws + 8388608);      // [8,16)
  const size_t W0 = 16777216;                                 // [16,64) attn weights
  unsigned short* wqkvTh = (unsigned short*)(ws + W0);
  unsigned short* wqkvTl = (unsigned short*)(ws + W0 + 20971520);
  unsigned short* woTh = (unsigned short*)(ws + W0);          // after QKV gemm
  unsigned short* woTl = (unsigned short*)(ws + W0 + 16777216);
  const size_t X0 = 67108864;                                 // [64,104) qkv
  float* qkv = (float*)(ws + X0);
  const size_t A0 = 109051904;                                // [104,136) attn out
  unsigned short* aoh = (unsigned short*)(ws + A0);
  unsigned short* aol = (unsigned short*)(ws + A0 + 16777216);
  unsigned short* vth = (unsigned short*)(ws + 142606336);    // [136,138)
  unsigned short* vtl = (unsigned short*)(ws + 144703488);    // [138,140)
  // MoE phase (all pre-MoE data dead when each region is written):
  unsigned short* moeGU = (unsigned short*)(ws + 16777216);   // [16,112)  E x 1536 x 2048 bf16 (interleaved gate/up rows)
  unsigned short* actb = (unsigned short*)(ws + 117440512);   // [112,118.3) 4096 x 768 bf16 (GU GEMM epilogue)
  unsigned short* moeD = (unsigned short*)(ws + 16777216);    // [16,64)   E x 2048 x 768 bf16 (after GU GEMM)
  float* eo = (float*)(ws + 67108864);                        // [64,96)   4096 x 2048 fp32 (qkv dead by then)
  const size_t RT = 146800640;                                // [140,...) router scratch
  float* pslot = (float*)(ws + RT);
  int* topi = (int*)(ws + RT + 16384);
  int* counts = (int*)(ws + RT + 32768);
  int* fill = counts + 16;
  int* offs = fill + 16;
  int* gtok = (int*)(ws + RT + 33280);
  int* destb = gtok + 2 * T;

  // 1. QKV weight transposes (split hi/lo, B^T layout)
  transpose_f32_bf16<<<dim3(128, 64, 1), 256, 0, stream>>>(wq, wqkvTh, wqkvTl, Dd, 4096, 4096, 2048, 0, 0);
  transpose_f32_bf16<<<dim3(16, 64, 1), 256, 0, stream>>>(wk, wqkvTh + (size_t)4096 * 2048, wqkvTl + (size_t)4096 * 2048, Dd, 512, 512, 2048, 0, 0);
  transpose_f32_bf16<<<dim3(16, 64, 1), 256, 0, stream>>>(wv, wqkvTh + (size_t)4608 * 2048, wqkvTl + (size_t)4608 * 2048, Dd, 512, 512, 2048, 0, 0);
  // 2. pre-RMS (split bf16)
  rms_kernel<<<T, 256, 0, stream>>>(x, pre_s, nullptr, hbh, hbl);
  // 3. fused QKV split GEMM -> qkv fp32 (T x 5120); 2-D XCD partition, 2-buf
  gemm_bt<true, 2><<<32 * 40, 256, 0, stream>>>(hbh, hbl, wqkvTh, wqkvTl, nullptr, qkv,
                                                T, QKVN, Dd, 32, 40, 1,
                                                nullptr, nullptr, nullptr, 0, nullptr, 0);
  // 4. qk norm + rope, in-place split-bf16
  qknorm_rope<<<T * HQ / 4, 256, 0, stream>>>(qkv, qns, pos, HQ, 0);
  qknorm_rope<<<T * HKV / 4, 256, 0, stream>>>(qkv, kns, pos, HKV, 4096);
  // 5. V transpose -> vt[b][kvh][d][s] split bf16
  for (int b = 0; b < Bb; ++b)
    transpose_f32_bf16<<<dim3(4, 32, HKV), 256, 0, stream>>>(
        qkv + (size_t)b * Ss * QKVN + 4608, vth + (size_t)b * HKV * 131072,
        vtl + (size_t)b * HKV * 131072, Ss, HD, QKVN, Ss, 128, 131072);
  // 6. wo transpose (split) into W region (wqkvT dead)
  transpose_f32_bf16<<<dim3(64, 128, 1), 256, 0, stream>>>(wo, woTh, woTl, 4096, Dd, 2048, 4096, 0, 0);
  // 7. split MFMA flash attention (LDS dbuf prefetch) -> ao hi/lo
  flash_mfma<<<dim3(Ss / 64, Bb * HQ), 256, 0, stream>>>((const char*)(ws + X0), vth, vtl, aoh, aol);
  // 8. O-proj split GEMM + residual -> out fp32; 2-D XCD partition, 2-buf
  gemm_bt<true, 2><<<32 * 16, 256, 0, stream>>>(aoh, aol, woTh, woTl, x, out,
                                                T, Dd, HQ * HD, 32, 16, 1,
                                                nullptr, nullptr, nullptr, 0, nullptr, 0);
  // 9. post-RMS (bf16 for experts only; router recomputes RMS itself)
  rms_kernel<<<T, 256, 0, stream>>>(out, post_s, nullptr, hbh, nullptr);
  // 10. router (fused RMS from `out`) + expert grouping
  hipMemsetAsync(counts, 0, 2 * E * sizeof(int), stream);
  router_kernel<<<T, 256, 0, stream>>>(out, post_s, rw, pslot, topi, counts);
  offsets_kernel<<<1, 64, 0, stream>>>(counts, offs);
  scatter_kernel<<<T / 256, 256, 0, stream>>>(topi, offs, fill, gtok, destb);
  // 11. MoE: gate/up transposed INTERLEAVED (gate col j -> row 2j, up -> 2j+1)
  transpose_f32_bf16<<<dim3(24, 64, E), 256, 0, stream>>>(gw, moeGU, nullptr, Dd, I, I, 4096,
                                                          (long)Dd * I, (long)1536 * 2048);
  transpose_f32_bf16<<<dim3(24, 64, E), 256, 0, stream>>>(uw, moeGU + 2048, nullptr, Dd, I, I, 4096,
                                                          (long)Dd * I, (long)1536 * 2048);
  // 12. ONE grouped GEMM with fused silu epilogue -> actb bf16 (4-buf+T5, expert-pinned XCDs)
  gemm_bt<false, 4><<<32 * 12 * E, 256, 0, stream>>>(hbh, nullptr, moeGU, nullptr, nullptr, nullptr,
                                                     0, 1536, Dd, 32, 12, E,
                                                     gtok, nullptr, offs, (long)1536 * 2048,
                                                     actb, I);
  // 13. down: transpose then grouped GEMM (4-buf+T5, expert-pinned XCDs), scatter rows
  transpose_f32_bf16<<<dim3(64, 24, E), 256, 0, stream>>>(dw, moeD, nullptr, I, Dd, Dd, I,
                                                          (long)I * Dd, (long)Dd * I);
  gemm_bt<false, 4><<<32 * 16 * E, 256, 0, stream>>>(actb, nullptr, moeD, nullptr, nullptr, eo,
                                                     0, Dd, I, 32, 16, E,
                                                     nullptr, destb, offs, (long)Dd * I,
                                                     nullptr, 0);
  // 14. weighted combine into residual (float4)
  combine_kernel<<<(T * Dd / 4) / 256, 256, 0, stream>>>(out, eo, pslot);
}

// Round 18
// 754.673 us; speedup vs baseline: 1.0411x; 1.0113x over previous
//
#include <hip/hip_runtime.h>
#include <math.h>

namespace {

constexpr int Bb = 2, Ss = 1024, Dd = 2048;
constexpr int HQ = 32, HKV = 4, HD = 128;
constexpr int E = 16, I = 768;
constexpr int T = Bb * Ss;                 // 2048 tokens
constexpr int QKVN = HQ * HD + 2 * HKV * HD;  // 5120
constexpr float EPS = 1e-6f;

typedef __attribute__((ext_vector_type(8))) short short8v;
typedef __attribute__((ext_vector_type(4))) float f32x4;
typedef __attribute__((ext_vector_type(4))) unsigned short ushort4v;

__device__ __forceinline__ unsigned short f2bf(float f) {
  unsigned u = __float_as_uint(f);
  u += 0x7fffu + ((u >> 16) & 1u);   // RNE
  return (unsigned short)(u >> 16);
}
__device__ __forceinline__ float bf2f(unsigned short h) {
  return __uint_as_float((unsigned)h << 16);
}

// global(16B per lane) -> LDS direct; lds_dst must be wave-uniform.
__device__ __forceinline__ void gld_lds16(const void* gsrc, void* lds_dst) {
  __builtin_amdgcn_global_load_lds(
      (const __attribute__((address_space(1))) void*)(unsigned long long)gsrc,
      (__attribute__((address_space(3))) void*)(unsigned)(unsigned long long)lds_dst,
      16, 0, 0);
}

// ---------------- RMS norm over D=2048; fp32 / bf16-hi / bf16-lo outputs ----------------
__global__ __launch_bounds__(256) void rms_kernel(const float* __restrict__ x,
                                                  const float* __restrict__ scale,
                                                  float* __restrict__ outf,
                                                  unsigned short* __restrict__ outh,
                                                  unsigned short* __restrict__ outl) {
  int row = blockIdx.x;
  const float* xr = x + (size_t)row * Dd;
  float ss = 0.f;
  for (int i = threadIdx.x; i < Dd; i += 256) { float v = xr[i]; ss += v * v; }
#pragma unroll
  for (int o = 32; o > 0; o >>= 1) ss += __shfl_xor(ss, o);
  __shared__ float red[4];
  int wave = threadIdx.x >> 6, lane = threadIdx.x & 63;
  if (lane == 0) red[wave] = ss;
  __syncthreads();
  __shared__ float s_r;
  if (threadIdx.x == 0) {
    float tot = red[0] + red[1] + red[2] + red[3];
    s_r = rsqrtf(tot / (float)Dd + EPS);
  }
  __syncthreads();
  float r = s_r;
  for (int i = threadIdx.x; i < Dd; i += 256) {
    float v = xr[i] * r * scale[i];
    if (outf) outf[(size_t)row * Dd + i] = v;
    if (outh) {
      unsigned short hv = f2bf(v);
      outh[(size_t)row * Dd + i] = hv;
      if (outl) outl[(size_t)row * Dd + i] = f2bf(v - bf2f(hv));
    }
  }
}

// ---------------- vectorized tiled fp32 -> bf16(hi[,lo]) transpose ----------------
// 64x64 tile: float4 loads, fp32 LDS with XOR swizzle (col ^= ((row>>2)&15)<<2),
// ushort4 stores (128B contiguous per wave-row). out[C][R] = in[R][C].
// Grid: (C/64, R/64, Z).
template <bool HAS_LO>
__global__ __launch_bounds__(256) void transpose_f32_bf16(
    const float* __restrict__ in, unsigned short* __restrict__ outh,
    unsigned short* __restrict__ outl,
    long in_rs, long out_rs, long in_bs, long out_bs) {
  __shared__ float tile[64][64];
  const float* inb = in + (size_t)blockIdx.z * in_bs;
  int r0 = blockIdx.y * 64, c0 = blockIdx.x * 64;
  int lr = threadIdx.x >> 4;          // 0..15
  int lc = (threadIdx.x & 15) * 4;    // 0,4,..,60
#pragma unroll
  for (int i = 0; i < 4; ++i) {
    int r = lr + i * 16;
    f32x4 v = *(const f32x4*)(inb + (size_t)(r0 + r) * in_rs + c0 + lc);
    *(f32x4*)&tile[r][lc ^ (((r >> 2) & 15) << 2)] = v;
  }
  __syncthreads();
  int oc = threadIdx.x >> 4;          // out-row-in-tile base (input col)
  int g = threadIdx.x & 15;           // group of 4 consecutive R values
#pragma unroll
  for (int i = 0; i < 4; ++i) {
    int c = oc + i * 16;              // input col = output row
    float vv[4];
#pragma unroll
    for (int j = 0; j < 4; ++j)
      vv[j] = tile[g * 4 + j][c ^ (g << 2)];   // row=g*4+j -> (row>>2)&15 == g
    ushort4v hq, lq;
#pragma unroll
    for (int j = 0; j < 4; ++j) {
      unsigned short hv = f2bf(vv[j]);
      hq[j] = hv;
      if (HAS_LO) lq[j] = f2bf(vv[j] - bf2f(hv));
    }
    size_t ob = (size_t)blockIdx.z * out_bs + (size_t)(c0 + c) * out_rs + r0 + g * 4;
    *(ushort4v*)(outh + ob) = hq;
    if (HAS_LO) *(ushort4v*)(outl + ob) = lq;
  }
}

// ---------------- bf16 MFMA GEMM, 64x128 tile ----------------
// C = A(MxK) * BT(NxK)^T (+Cadd). SPLIT: 3-term hi/lo (~fp32 precision).
// NBUF=2: dbuf prefetch (drain) — best for split (48 KB LDS, 2+ blocks/CU).
// NBUF=4: counted-vmcnt pipeline (3 tiles in flight) + T5 setprio — non-split MoE.
// 1-D launch, XCD-aware decode:
//   dense (nE==1): 2-D partition — each XCD owns an (M/2 x N/4) rectangle.
//   MoE  (nE>1):  ALL blocks of expert e land on XCD e&7.
// MoE mode via offs/gtok/destb. Cact!=null: paired-silu epilogue.
template <bool SPLIT, int NBUF>
__global__ __launch_bounds__(256) void gemm_bt(
    const unsigned short* __restrict__ Ah, const unsigned short* __restrict__ Al,
    const unsigned short* __restrict__ Bh, const unsigned short* __restrict__ Bl,
    const float* __restrict__ Cadd, float* __restrict__ C,
    int M, int N, int K, int nMb, int nNb, int nE,
    const int* __restrict__ gtok, const int* __restrict__ destb,
    const int* __restrict__ offs, long bt_estride,
    unsigned short* __restrict__ Cact, int ldact) {
  constexpr int NP = SPLIT ? 2 : 1;
  __shared__ alignas(16) unsigned short As[NBUF][NP][64 * 32];
  __shared__ alignas(16) unsigned short Bs[NBUF][NP][128 * 32];
  int bid = blockIdx.x;
  int xcd = bid & 7, rest = bid >> 3;
  int mIdx, nIdx, eIdx;
  if (nE > 1) {
    // expert-major: expert e pinned to XCD e&7 (nE % 8 == 0)
    int gpe = nMb * nNb;                  // blocks per expert
    eIdx = xcd + 8 * (rest / gpe);
    int rem = rest % gpe;
    mIdx = rem % nMb;
    nIdx = rem / nMb;
    if (eIdx >= nE) return;
  } else {
    // dense 2-D: xcd = mh*4 + nq; rest = lm + (nMb/2)*ln  (nMb%2==0, nNb%4==0)
    int nMh = nMb >> 1, nNq = nNb >> 2;
    int mh = xcd >> 2, nq = xcd & 3;
    int lm = rest % nMh, ln = rest / nMh;
    if (ln >= nNq) return;
    mIdx = mh * nMh + lm;
    nIdx = nq * nNq + ln;
    eIdx = 0;
  }

  int base = 0, rows = M;
  const unsigned short* bth = Bh;
  const unsigned short* btl = Bl;
  if (offs) {
    base = offs[eIdx];
    rows = offs[eIdx + 1] - base;
    bth = Bh + (size_t)eIdx * bt_estride;
    if (SPLIT) btl = Bl + (size_t)eIdx * bt_estride;
  }
  int rb = mIdx * 64;
  if (rb >= rows) return;
  int cb = nIdx * 128;
  int tid = threadIdx.x, w = tid >> 6, l = tid & 63;

  // A staging: one row per thread. row = w*16 + (l>>2), k-chunk (l&3)*8.
  size_t ga;
  {
    int ra = rb + w * 16 + (l >> 2);
    if (ra >= rows) ra = rows - 1;
    int gg = offs ? (gtok ? gtok[base + ra] : (base + ra)) : ra;
    ga = (size_t)gg * K + (l & 3) * 8;
  }
  // B staging: two rows per thread: w*32 + j*16 + (l>>2).
  size_t gb0 = (size_t)(cb + w * 32 + (l >> 2)) * K + (l & 3) * 8;
  size_t gb1 = gb0 + (size_t)16 * K;
  unsigned dA = (unsigned)w * 1024;               // LDS byte offsets (wave-uniform)
  unsigned dB0 = (unsigned)w * 2048;
  unsigned dB1 = dB0 + 1024;

  int wr = (w >> 1) * 32, wc = (w & 1) * 64;
  int lrow = l & 15;
  unsigned lk = (unsigned)(l >> 4) * 16;          // byte offset along K
  f32x4 acc[2][4] = {};

  auto STAGE = [&](int buf, int k0) {
    gld_lds16(Ah + ga + k0, (char*)As[buf][0] + dA);
    gld_lds16(bth + gb0 + k0, (char*)Bs[buf][0] + dB0);
    gld_lds16(bth + gb1 + k0, (char*)Bs[buf][0] + dB1);
    if constexpr (SPLIT) {
      gld_lds16(Al + ga + k0, (char*)As[buf][1] + dA);
      gld_lds16(btl + gb0 + k0, (char*)Bs[buf][1] + dB0);
      gld_lds16(btl + gb1 + k0, (char*)Bs[buf][1] + dB1);
    }
  };
  auto COMPUTE = [&](int buf) {
    short8v afh[2], bfh[4];
#pragma unroll
    for (int mi = 0; mi < 2; ++mi)
      afh[mi] = *(const short8v*)((char*)As[buf][0] + (unsigned)(wr + mi * 16 + lrow) * 64 + lk);
#pragma unroll
    for (int ni = 0; ni < 4; ++ni)
      bfh[ni] = *(const short8v*)((char*)Bs[buf][0] + (unsigned)(wc + ni * 16 + lrow) * 64 + lk);
    if constexpr (SPLIT) {
      short8v afl[2], bfl[4];
#pragma unroll
      for (int mi = 0; mi < 2; ++mi)
        afl[mi] = *(const short8v*)((char*)As[buf][1] + (unsigned)(wr + mi * 16 + lrow) * 64 + lk);
#pragma unroll
      for (int ni = 0; ni < 4; ++ni)
        bfl[ni] = *(const short8v*)((char*)Bs[buf][1] + (unsigned)(wc + ni * 16 + lrow) * 64 + lk);
#pragma unroll
      for (int mi = 0; mi < 2; ++mi)
#pragma unroll
        for (int ni = 0; ni < 4; ++ni) {
          acc[mi][ni] = __builtin_amdgcn_mfma_f32_16x16x32_bf16(afh[mi], bfh[ni], acc[mi][ni], 0, 0, 0);
          acc[mi][ni] = __builtin_amdgcn_mfma_f32_16x16x32_bf16(afl[mi], bfh[ni], acc[mi][ni], 0, 0, 0);
          acc[mi][ni] = __builtin_amdgcn_mfma_f32_16x16x32_bf16(afh[mi], bfl[ni], acc[mi][ni], 0, 0, 0);
        }
    } else {
#pragma unroll
      for (int mi = 0; mi < 2; ++mi)
#pragma unroll
        for (int ni = 0; ni < 4; ++ni)
          acc[mi][ni] = __builtin_amdgcn_mfma_f32_16x16x32_bf16(afh[mi], bfh[ni], acc[mi][ni], 0, 0, 0);
    }
  };

  int NT = K / 32;
  if constexpr (NBUF == 2) {
    STAGE(0, 0);
    asm volatile("s_waitcnt vmcnt(0)" ::: "memory");
    __syncthreads();
    int cur = 0;
    for (int t = 0; t < NT; ++t) {
      if (t + 1 < NT) STAGE(cur ^ 1, (t + 1) * 32);
      COMPUTE(cur);
      asm volatile("s_waitcnt vmcnt(0)" ::: "memory");
      __syncthreads();
      cur ^= 1;
    }
  } else {
    // 4-buf: 3 tiles in flight, counted vmcnt (L=3 or 6 loads/STAGE), raw barrier.
    // T5: setprio(1) around the MFMA cluster — pays on role-split schedules.
    STAGE(0, 0);
    if (NT > 1) STAGE(1, 32);
    if (NT > 2) STAGE(2, 64);
    for (int t = 0; t < NT; ++t) {
      if (t + 2 < NT) {
        if constexpr (SPLIT) asm volatile("s_waitcnt vmcnt(12)" ::: "memory");
        else                 asm volatile("s_waitcnt vmcnt(6)" ::: "memory");
      } else if (t + 1 < NT) {
        if constexpr (SPLIT) asm volatile("s_waitcnt vmcnt(6)" ::: "memory");
        else                 asm volatile("s_waitcnt vmcnt(3)" ::: "memory");
      } else {
        asm volatile("s_waitcnt vmcnt(0)" ::: "memory");
      }
      __builtin_amdgcn_s_barrier();   // all waves' tile-t stages visible; bounds skew
      if (t + 3 < NT) STAGE((t + 3) & 3, (t + 3) * 32);
      __builtin_amdgcn_s_setprio(1);
      COMPUTE(t & 3);
      __builtin_amdgcn_s_setprio(0);
    }
  }

  int lr4 = (l >> 4) << 2;
  if (Cact) {
    // paired-silu epilogue: n even = gate, n odd = up (same logical col n>>1)
#pragma unroll
    for (int mi = 0; mi < 2; ++mi) {
#pragma unroll
      for (int reg = 0; reg < 4; ++reg) {
        int rl = wr + mi * 16 + lr4 + reg;
        int rr = rb + rl;
        bool valid = !(offs && rr >= rows);
        size_t orow = 0;
        if (valid) orow = (size_t)(destb ? destb[base + rr] : (base + rr));
#pragma unroll
        for (int ni = 0; ni < 4; ++ni) {
          float v = acc[mi][ni][reg];
          float other = __shfl_xor(v, 1);
          if (valid && !(l & 1)) {
            float s = 1.f / (1.f + __expf(-v));
            int n = cb + wc + ni * 16 + (l & 15);
            Cact[orow * (size_t)ldact + (n >> 1)] = f2bf(v * s * other);
          }
        }
      }
    }
  } else {
#pragma unroll
    for (int mi = 0; mi < 2; ++mi) {
#pragma unroll
      for (int reg = 0; reg < 4; ++reg) {
        int rl = wr + mi * 16 + lr4 + reg;
        int rr = rb + rl;
        if (offs && rr >= rows) continue;
        size_t orow;
        if (!offs) orow = (size_t)rr;
        else orow = (size_t)(destb ? destb[base + rr] : (base + rr));
        float* crow = C + orow * N + cb + wc + (l & 15);
        const float* arow = Cadd ? (Cadd + orow * N + cb + wc + (l & 15)) : nullptr;
#pragma unroll
        for (int ni = 0; ni < 4; ++ni) {
          float v = acc[mi][ni][reg];
          if (Cadd) v += arow[ni * 16];
          crow[ni * 16] = v;
        }
      }
    }
  }
}

// ---------------- per-head RMS + mROPE, IN-PLACE split-bf16 conversion ----------------
__global__ __launch_bounds__(256) void qknorm_rope(
    float* __restrict__ qkv, const float* __restrict__ scale,
    const int* __restrict__ pos, int H, int coff) {
  int wid = (blockIdx.x * 256 + threadIdx.x) >> 6;
  int lane = threadIdx.x & 63;
  int t = wid / H, hh = wid % H;
  float* row = qkv + (size_t)t * QKVN + coff + hh * 128;
  float v0 = row[lane], v1 = row[lane + 64];
  float ss = v0 * v0 + v1 * v1;
#pragma unroll
  for (int o = 32; o > 0; o >>= 1) ss += __shfl_xor(ss, o);
  float r = rsqrtf(ss / 128.f + EPS);
  float n0 = v0 * r * scale[lane];
  float n1 = v1 * r * scale[lane + 64];
  int axis = lane < 24 ? 0 : (lane < 44 ? 1 : 2);
  float p = (float)pos[axis * T + t];
  float inv = exp2f(-19.931568569324174f * ((float)lane * (1.0f / 64.0f)));
  float f = p * inv;
  float sn, cs;
  sincosf(f, &sn, &cs);
  float o0 = n0 * cs - n1 * sn;
  float o1 = n1 * cs + n0 * sn;
  unsigned short h0 = f2bf(o0), h1 = f2bf(o1);
  unsigned short* o = (unsigned short*)row;
  o[lane] = h0;
  o[lane + 64] = h1;
  o[128 + lane] = f2bf(o0 - bf2f(h0));
  o[192 + lane] = f2bf(o1 - bf2f(h1));
}

// ---------------- MFMA causal GQA flash attention, split-bf16 (3-term) ----------------
// LDS-staged K/V, double-buffered with async prefetch (one barrier per KV tile).
// Lazy defer-max (shuffle tree only when max grows >8), lsum via MFMA-ones,
// fully-masked-tile compute skip, LPT launch order (heavy q-tiles first).
__global__ __launch_bounds__(256) void flash_mfma(
    const char* __restrict__ qkvb, const unsigned short* __restrict__ Vth,
    const unsigned short* __restrict__ Vtl,
    unsigned short* __restrict__ Aoh, unsigned short* __restrict__ Aol) {
  __shared__ alignas(16) unsigned short Ks[2][2][32 * 128];   // [buf][hi/lo][key][d], swizzled
  __shared__ alignas(16) unsigned short Vs[2][2][128 * 32];   // [buf][hi/lo][d][key], swizzled
  __shared__ alignas(16) unsigned short Ps[2][4 * 16 * 32];   // [hi/lo] per-wave [q][key]
  int by = blockIdx.y;
  int b = by >> 5, h = by & 31, kvh = h >> 3;
  int qb0 = (int)(gridDim.x - 1 - blockIdx.x) * 64;   // LPT: heavy blocks first
  int tid = threadIdx.x, w = tid >> 6, l = tid & 63;

  short8v aqh[4], aql[4];
  {
    const char* qrow = qkvb + (size_t)(b * Ss + qb0 + w * 16 + (l & 15)) * 20480
                       + h * 512 + (l >> 4) * 16;
#pragma unroll
    for (int kc = 0; kc < 4; ++kc) {
      aqh[kc] = *(const short8v*)(qrow + kc * 64);
      aql[kc] = *(const short8v*)(qrow + 256 + kc * 64);
    }
  }
  short8v vone;
#pragma unroll
  for (int j = 0; j < 8; ++j) vone[j] = (short)0x3F80;   // bf16 1.0
  f32x4 oacc[8] = {};
  float mrow[4], lsum[4];
#pragma unroll
  for (int r = 0; r < 4; ++r) { mrow[r] = -1e30f; lsum[r] = 0.f; }
  const float sc = 0.08838834764831845f;  // 1/sqrt(128)
  int qgbase = qb0 + w * 16 + ((l >> 4) << 2);
  int ntiles = qb0 / 32 + 2;              // block-uniform (barrier-synced loop)
  int wmaxrow = qb0 + w * 16 + 15;        // this wave's last q row

  auto STAGE = [&](int buf, int kt) {
#pragma unroll
    for (int j = 0; j < 2; ++j) {
      int row = w * 8 + j * 4 + (l >> 4);
      unsigned scol = (unsigned)((l & 15) * 16) ^ ((unsigned)(row & 7) << 4);
      const char* src = qkvb + (size_t)(b * Ss + kt * 32 + row) * 20480
                        + 16384 + kvh * 512 + scol;
      gld_lds16(src, (char*)Ks[buf][0] + (w * 8 + j * 4) * 256);
      gld_lds16(src + 256, (char*)Ks[buf][1] + (w * 8 + j * 4) * 256);
    }
#pragma unroll
    for (int j = 0; j < 2; ++j) {
      int d = w * 32 + j * 16 + (l >> 2);
      unsigned scol = (unsigned)((l & 3) * 16) ^ ((unsigned)(d & 3) << 4);
      size_t vo = (((size_t)(b * HKV + kvh) * 128 + d) * 1024 + kt * 32) * 2 + scol;
      gld_lds16((const char*)Vth + vo, (char*)Vs[buf][0] + (w * 32 + j * 16) * 64);
      gld_lds16((const char*)Vtl + vo, (char*)Vs[buf][1] + (w * 32 + j * 16) * 64);
    }
  };

  STAGE(0, 0);
  asm volatile("s_waitcnt vmcnt(0)" ::: "memory");
  __syncthreads();

  int cur = 0;
  for (int kt = 0; kt < ntiles; ++kt) {
    if (kt + 1 < ntiles) STAGE(cur ^ 1, kt + 1);

    if (kt * 32 <= wmaxrow) {   // wave has at least one unmasked key this tile
      f32x4 s[2] = {};
#pragma unroll
      for (int nt = 0; nt < 2; ++nt) {
        int krow = nt * 16 + (l & 15);
#pragma unroll
        for (int kc = 0; kc < 4; ++kc) {
          unsigned colb = ((unsigned)(kc * 64 + (l >> 4) * 16)) ^ ((unsigned)(krow & 7) << 4);
          short8v bkh = *(const short8v*)((char*)Ks[cur][0] + (unsigned)krow * 256 + colb);
          short8v bkl = *(const short8v*)((char*)Ks[cur][1] + (unsigned)krow * 256 + colb);
          s[nt] = __builtin_amdgcn_mfma_f32_16x16x32_bf16(aqh[kc], bkh, s[nt], 0, 0, 0);
          s[nt] = __builtin_amdgcn_mfma_f32_16x16x32_bf16(aql[kc], bkh, s[nt], 0, 0, 0);
          s[nt] = __builtin_amdgcn_mfma_f32_16x16x32_bf16(aqh[kc], bkl, s[nt], 0, 0, 0);
        }
      }
      // mask + per-lane tile max (no reduction in common path)
      float pv[2][4], tmax[4];
#pragma unroll
      for (int r = 0; r < 4; ++r) tmax[r] = -1e30f;
#pragma unroll
      for (int nt = 0; nt < 2; ++nt) {
        int key = kt * 32 + nt * 16 + (l & 15);
#pragma unroll
        for (int r = 0; r < 4; ++r) {
          float v = s[nt][r] * sc;
          if (key > qgbase + r) v = -1e30f;
          pv[nt][r] = v;
          tmax[r] = fmaxf(tmax[r], v);
        }
      }
      // lazy defer-max: tree + rescale only when some lane's max grew > 8
      bool need = false;
#pragma unroll
      for (int r = 0; r < 4; ++r) need = need || (tmax[r] > mrow[r] + 8.f);
      if (__any(need)) {
#pragma unroll
        for (int o = 1; o < 16; o <<= 1)
#pragma unroll
          for (int r = 0; r < 4; ++r) tmax[r] = fmaxf(tmax[r], __shfl_xor(tmax[r], o));
#pragma unroll
        for (int r = 0; r < 4; ++r) {
          float mn = fmaxf(mrow[r], tmax[r]);
          float corr = __expf(mrow[r] - mn);
          mrow[r] = mn;
          lsum[r] *= corr;
#pragma unroll
          for (int n2 = 0; n2 < 8; ++n2) oacc[n2][r] *= corr;
        }
      }
      // P = exp(S - mrow) (bounded by e^8), split to bf16 hi/lo in LDS
#pragma unroll
      for (int nt = 0; nt < 2; ++nt)
#pragma unroll
        for (int r = 0; r < 4; ++r) {
          float p = __expf(pv[nt][r] - mrow[r]);
          unsigned short ph = f2bf(p);
          unsigned short pl = f2bf(p - bf2f(ph));
          int q = ((l >> 4) << 2) + r;
          int key = nt * 16 + (l & 15);
          unsigned pb = w * 1024 + q * 64 + (((unsigned)key * 2) ^ ((unsigned)(q & 3) << 4));
          *(unsigned short*)((char*)Ps[0] + pb) = ph;
          *(unsigned short*)((char*)Ps[1] + pb) = pl;
        }
      unsigned pr = w * 1024 + (l & 15) * 64 +
                    (((unsigned)(l >> 4) * 16) ^ ((unsigned)(l & 3) << 4));
      short8v pah = *(const short8v*)((char*)Ps[0] + pr);
      short8v pal = *(const short8v*)((char*)Ps[1] + pr);
      // row-sum via MFMA with ones-B: out[q][*] = sum_k P[q][k], layout matches lsum[r]
      {
        f32x4 rs = {};
        rs = __builtin_amdgcn_mfma_f32_16x16x32_bf16(pah, vone, rs, 0, 0, 0);
        rs = __builtin_amdgcn_mfma_f32_16x16x32_bf16(pal, vone, rs, 0, 0, 0);
#pragma unroll
        for (int r = 0; r < 4; ++r) lsum[r] += rs[r];
      }
#pragma unroll
      for (int n2 = 0; n2 < 8; ++n2) {
        int d = n2 * 16 + (l & 15);
        unsigned vb = (unsigned)d * 64 +
                      (((unsigned)(l >> 4) * 16) ^ ((unsigned)(d & 3) << 4));
        short8v bvh = *(const short8v*)((char*)Vs[cur][0] + vb);
        short8v bvl = *(const short8v*)((char*)Vs[cur][1] + vb);
        oacc[n2] = __builtin_amdgcn_mfma_f32_16x16x32_bf16(pah, bvh, oacc[n2], 0, 0, 0);
        oacc[n2] = __builtin_amdgcn_mfma_f32_16x16x32_bf16(pal, bvh, oacc[n2], 0, 0, 0);
        oacc[n2] = __builtin_amdgcn_mfma_f32_16x16x32_bf16(pah, bvl, oacc[n2], 0, 0, 0);
      }
    }
    asm volatile("s_waitcnt vmcnt(0)" ::: "memory");
    __syncthreads();
    cur ^= 1;
  }
#pragma unroll
  for (int r = 0; r < 4; ++r) {
    float inv = 1.f / lsum[r];
    size_t obase = (size_t)(b * Ss + qgbase + r) * 4096 + h * 128 + (l & 15);
#pragma unroll
    for (int n2 = 0; n2 < 8; ++n2) {
      float v = oacc[n2][r] * inv;
      unsigned short hv = f2bf(v);
      Aoh[obase + n2 * 16] = hv;
      Aol[obase + n2 * 16] = f2bf(v - bf2f(hv));
    }
  }
}

// ---------------- router: fused RMS (identical reduction to rms_kernel) + top-2 ----------------
__global__ __launch_bounds__(256) void router_kernel(const float* __restrict__ X,
                                                     const float* __restrict__ scale,
                                                     const float* __restrict__ RW,
                                                     float* __restrict__ pslot,
                                                     int* __restrict__ topi,
                                                     int* __restrict__ counts) {
  int t = blockIdx.x;
  const float* xr = X + (size_t)t * Dd;
  float ss = 0.f;
  for (int i = threadIdx.x; i < Dd; i += 256) { float v = xr[i]; ss += v * v; }
#pragma unroll
  for (int o = 32; o > 0; o >>= 1) ss += __shfl_xor(ss, o);
  __shared__ float red[4];
  int wave = threadIdx.x >> 6, lane = threadIdx.x & 63;
  if (lane == 0) red[wave] = ss;
  __syncthreads();
  __shared__ float s_r;
  if (threadIdx.x == 0) {
    float tot = red[0] + red[1] + red[2] + red[3];
    s_r = rsqrtf(tot / (float)Dd + EPS);
  }
  __syncthreads();
  float r = s_r;
  float part[E] = {};
  for (int i = threadIdx.x; i < Dd; i += 256) {
    float hv = xr[i] * r * scale[i];
    const float* rwp = RW + (size_t)i * E;
#pragma unroll
    for (int e = 0; e < E; ++e) part[e] = fmaf(hv, rwp[e], part[e]);
  }
#pragma unroll
  for (int e = 0; e < E; ++e)
#pragma unroll
    for (int o = 32; o > 0; o >>= 1) part[e] += __shfl_xor(part[e], o);
  __shared__ float pr[4][E];
  if (lane == 0)
#pragma unroll
    for (int e = 0; e < E; ++e) pr[wave][e] = part[e];
  __syncthreads();
  if (threadIdx.x == 0) {
    float lg[E];
#pragma unroll
    for (int e = 0; e < E; ++e) lg[e] = pr[0][e] + pr[1][e] + pr[2][e] + pr[3][e];
    float mx = lg[0];
#pragma unroll
    for (int e = 1; e < E; ++e) mx = fmaxf(mx, lg[e]);
    float p[E];
#pragma unroll
    for (int e = 0; e < E; ++e) p[e] = __expf(lg[e] - mx);
    int i0 = 0;
#pragma unroll
    for (int e = 1; e < E; ++e) if (p[e] > p[i0]) i0 = e;
    int i1 = (i0 == 0) ? 1 : 0;
#pragma unroll
    for (int e = 0; e < E; ++e) if (e != i0 && p[e] > p[i1]) i1 = e;
    float p0 = p[i0], p1 = p[i1];
    float denom = p0 + p1;
    pslot[2 * t] = p0 / denom;
    pslot[2 * t + 1] = p1 / denom;
    topi[2 * t] = i0;
    topi[2 * t + 1] = i1;
    atomicAdd(&counts[i0], 1);
    atomicAdd(&counts[i1], 1);
  }
}

__global__ void offsets_kernel(const int* __restrict__ counts, int* __restrict__ offs) {
  if (threadIdx.x == 0) {
    int s = 0;
    for (int e = 0; e < E; ++e) { offs[e] = s; s += counts[e]; }
    offs[E] = s;
  }
}

__global__ __launch_bounds__(256) void scatter_kernel(const int* __restrict__ topi,
                                                      const int* __restrict__ offs,
                                                      int* __restrict__ fill,
                                                      int* __restrict__ gtok,
                                                      int* __restrict__ destb) {
  int t = blockIdx.x * 256 + threadIdx.x;
  if (t >= T) return;
#pragma unroll
  for (int slot = 0; slot < 2; ++slot) {
    int e = topi[2 * t + slot];
    int pos = offs[e] + atomicAdd(&fill[e], 1);
    gtok[pos] = t;
    destb[pos] = 2 * t + slot;
  }
}

// vectorized (float4) weighted combine into residual
__global__ __launch_bounds__(256) void combine_kernel(float* __restrict__ out,
                                                      const float* __restrict__ eo,
                                                      const float* __restrict__ pslot) {
  int g = blockIdx.x * 256 + threadIdx.x;  // < T*Dd/4
  int t = g >> 9;                          // 512 float4 groups per row
  int d4 = g & 511;
  float p0 = pslot[2 * t], p1 = pslot[2 * t + 1];
  const float4 a = *(const float4*)(eo + ((size_t)(2 * t) << 11) + d4 * 4);
  const float4 bq = *(const float4*)(eo + ((size_t)(2 * t + 1) << 11) + d4 * 4);
  float4* o = (float4*)(out + ((size_t)t << 11) + d4 * 4);
  float4 v = *o;
  v.x += p0 * a.x + p1 * bq.x;
  v.y += p0 * a.y + p1 * bq.y;
  v.z += p0 * a.z + p1 * bq.z;
  v.w += p0 * a.w + p1 * bq.w;
  *o = v;
}

}  // namespace

extern "C" void kernel_launch(void* const* d_in, const int* in_sizes, int n_in,
                              void* d_out, int out_size, void* d_ws, size_t ws_size,
                              hipStream_t stream) {
  (void)in_sizes; (void)n_in; (void)out_size; (void)ws_size;
  const float* x = (const float*)d_in[0];
  const int* pos = (const int*)d_in[1];
  const float* pre_s = (const float*)d_in[2];
  const float* wq = (const float*)d_in[3];
  const float* wk = (const float*)d_in[4];
  const float* wv = (const float*)d_in[5];
  const float* wo = (const float*)d_in[6];
  const float* qns = (const float*)d_in[7];
  const float* kns = (const float*)d_in[8];
  const float* post_s = (const float*)d_in[9];
  const float* rw = (const float*)d_in[10];
  const float* gw = (const float*)d_in[11];
  const float* uw = (const float*)d_in[12];
  const float* dw = (const float*)d_in[13];
  float* out = (float*)d_out;
  char* ws = (char*)d_ws;

  // ---- workspace (phase-aliased; MiB offsets; peak ~140 MiB) ----
  unsigned short* hbh = (unsigned short*)(ws + 0);            // [0,8)
  unsigned short* hbl = (unsigned short*)(ws + 8388608);      // [8,16)
  const size_t W0 = 16777216;                                 // [16,64) attn weights
  unsigned short* wqkvTh = (unsigned short*)(ws + W0);
  unsigned short* wqkvTl = (unsigned short*)(ws + W0 + 20971520);
  unsigned short* woTh = (unsigned short*)(ws + W0);          // after QKV gemm
  unsigned short* woTl = (unsigned short*)(ws + W0 + 16777216);
  const size_t X0 = 67108864;                                 // [64,104) qkv
  float* qkv = (float*)(ws + X0);
  const size_t A0 = 109051904;                                // [104,136) attn out
  unsigned short* aoh = (unsigned short*)(ws + A0);
  unsigned short* aol = (unsigned short*)(ws + A0 + 16777216);
  unsigned short* vth = (unsigned short*)(ws + 142606336);    // [136,138)
  unsigned short* vtl = (unsigned short*)(ws + 144703488);    // [138,140)
  // MoE phase (all pre-MoE data dead when each region is written):
  unsigned short* moeGU = (unsigned short*)(ws + 16777216);   // [16,112)  E x 1536 x 2048 bf16 (interleaved gate/up rows)
  unsigned short* actb = (unsigned short*)(ws + 117440512);   // [112,118.3) 4096 x 768 bf16 (GU GEMM epilogue)
  unsigned short* moeD = (unsigned short*)(ws + 16777216);    // [16,64)   E x 2048 x 768 bf16 (after GU GEMM)
  float* eo = (float*)(ws + 67108864);                        // [64,96)   4096 x 2048 fp32 (qkv dead by then)
  const size_t RT = 146800640;                                // [140,...) router scratch
  float* pslot = (float*)(ws + RT);
  int* topi = (int*)(ws + RT + 16384);
  int* counts = (int*)(ws + RT + 32768);
  int* fill = counts + 16;
  int* offs = fill + 16;
  int* gtok = (int*)(ws + RT + 33280);
  int* destb = gtok + 2 * T;

  // 1. QKV weight transposes (split hi/lo, B^T layout); vectorized 64x64 tiles
  transpose_f32_bf16<true><<<dim3(64, 32, 1), 256, 0, stream>>>(wq, wqkvTh, wqkvTl, 4096, 2048, 0, 0);
  transpose_f32_bf16<true><<<dim3(8, 32, 1), 256, 0, stream>>>(wk, wqkvTh + (size_t)4096 * 2048, wqkvTl + (size_t)4096 * 2048, 512, 2048, 0, 0);
  transpose_f32_bf16<true><<<dim3(8, 32, 1), 256, 0, stream>>>(wv, wqkvTh + (size_t)4608 * 2048, wqkvTl + (size_t)4608 * 2048, 512, 2048, 0, 0);
  // 2. pre-RMS (split bf16)
  rms_kernel<<<T, 256, 0, stream>>>(x, pre_s, nullptr, hbh, hbl);
  // 3. fused QKV split GEMM -> qkv fp32 (T x 5120); 2-D XCD partition, 2-buf
  gemm_bt<true, 2><<<32 * 40, 256, 0, stream>>>(hbh, hbl, wqkvTh, wqkvTl, nullptr, qkv,
                                                T, QKVN, Dd, 32, 40, 1,
                                                nullptr, nullptr, nullptr, 0, nullptr, 0);
  // 4. qk norm + rope, in-place split-bf16
  qknorm_rope<<<T * HQ / 4, 256, 0, stream>>>(qkv, qns, pos, HQ, 0);
  qknorm_rope<<<T * HKV / 4, 256, 0, stream>>>(qkv, kns, pos, HKV, 4096);
  // 5. V transpose -> vt[b][kvh][d][s] split bf16
  for (int b = 0; b < Bb; ++b)
    transpose_f32_bf16<true><<<dim3(2, 16, HKV), 256, 0, stream>>>(
        qkv + (size_t)b * Ss * QKVN + 4608, vth + (size_t)b * HKV * 131072,
        vtl + (size_t)b * HKV * 131072, QKVN, Ss, 128, 131072);
  // 6. wo transpose (split) into W region (wqkvT dead)
  transpose_f32_bf16<true><<<dim3(32, 64, 1), 256, 0, stream>>>(wo, woTh, woTl, 2048, 4096, 0, 0);
  // 7. split MFMA flash attention (LDS dbuf prefetch) -> ao hi/lo
  flash_mfma<<<dim3(Ss / 64, Bb * HQ), 256, 0, stream>>>((const char*)(ws + X0), vth, vtl, aoh, aol);
  // 8. O-proj split GEMM + residual -> out fp32; 2-D XCD partition, 2-buf
  gemm_bt<true, 2><<<32 * 16, 256, 0, stream>>>(aoh, aol, woTh, woTl, x, out,
                                                T, Dd, HQ * HD, 32, 16, 1,
                                                nullptr, nullptr, nullptr, 0, nullptr, 0);
  // 9. post-RMS (bf16 for experts only; router recomputes RMS itself)
  rms_kernel<<<T, 256, 0, stream>>>(out, post_s, nullptr, hbh, nullptr);
  // 10. router (fused RMS from `out`) + expert grouping
  hipMemsetAsync(counts, 0, 2 * E * sizeof(int), stream);
  router_kernel<<<T, 256, 0, stream>>>(out, post_s, rw, pslot, topi, counts);
  offsets_kernel<<<1, 64, 0, stream>>>(counts, offs);
  scatter_kernel<<<T / 256, 256, 0, stream>>>(topi, offs, fill, gtok, destb);
  // 11. MoE: gate/up transposed INTERLEAVED (gate col j -> row 2j, up -> 2j+1)
  transpose_f32_bf16<false><<<dim3(12, 32, E), 256, 0, stream>>>(gw, moeGU, nullptr, 768, 4096,
                                                                 (long)Dd * I, (long)1536 * 2048);
  transpose_f32_bf16<false><<<dim3(12, 32, E), 256, 0, stream>>>(uw, moeGU + 2048, nullptr, 768, 4096,
                                                                 (long)Dd * I, (long)1536 * 2048);
  // 12. ONE grouped GEMM with fused silu epilogue -> actb bf16 (4-buf+T5, expert-pinned XCDs)
  gemm_bt<false, 4><<<32 * 12 * E, 256, 0, stream>>>(hbh, nullptr, moeGU, nullptr, nullptr, nullptr,
                                                     0, 1536, Dd, 32, 12, E,
                                                     gtok, nullptr, offs, (long)1536 * 2048,
                                                     actb, I);
  // 13. down: transpose then grouped GEMM (4-buf+T5, expert-pinned XCDs), scatter rows
  transpose_f32_bf16<false><<<dim3(32, 12, E), 256, 0, stream>>>(dw, moeD, nullptr, 2048, 768,
                                                                 (long)I * Dd, (long)Dd * I);
  gemm_bt<false, 4><<<32 * 16 * E, 256, 0, stream>>>(actb, nullptr, moeD, nullptr, nullptr, eo,
                                                     0, Dd, I, 32, 16, E,
                                                     nullptr, destb, offs, (long)Dd * I,
                                                     nullptr, 0);
  // 14. weighted combine into residual (float4)
  combine_kernel<<<(T * Dd / 4) / 256, 256, 0, stream>>>(out, eo, pslot);
}